// Round 1
// baseline (2584.688 us; speedup 1.0000x reference)
//
#include <hip/hip_runtime.h>
#include <math.h>

#define F 64
#define HID 128

// ---------------------------------------------------------------------------
// index-width detection: reference declares int64, but JAX without x64 gives
// int32. Read first 1024 words as u64: true-int64 values are all < N; int32
// data packed into u64 is >= 2^32 with overwhelming probability.
__global__ void k_detect(const unsigned long long* p, int n, unsigned long long Nv, int* flag) {
    __shared__ int bad;
    if (threadIdx.x == 0) bad = 0;
    __syncthreads();
    for (int i = threadIdx.x; i < n; i += blockDim.x)
        if (p[i] >= Nv) bad = 1;
    __syncthreads();
    if (threadIdx.x == 0) *flag = bad ? 0 : 1;   // 1 = int64, 0 = int32
}

__device__ __forceinline__ int load_idx(const long long* e64, const int* e32, int f, size_t pos) {
    return f ? (int)e64[pos] : e32[pos];
}

// ---------------------------------------------------------------------------
__global__ void k_deg_init(float* deg, int n) {
    int i = blockIdx.x * 256 + threadIdx.x;
    if (i < n) deg[i] = 1.0f;               // self-loop weight
}

__global__ void k_deg_acc(const long long* ei64, const int* ei32, const int* flag,
                          const float* __restrict__ ew, float* deg, int E_) {
    int e = blockIdx.x * 256 + threadIdx.x;
    if (e >= E_) return;
    int f = *flag;
    int d = load_idx(ei64, ei32, f, (size_t)E_ + e);
    atomicAdd(&deg[d], ew[e]);
}

__global__ void k_dinv(float* deg, int n) {
    int i = blockIdx.x * 256 + threadIdx.x;
    if (i < n) { float v = deg[i]; deg[i] = v > 0.f ? rsqrtf(v) : 0.f; }
}

// ---------------------------------------------------------------------------
// C[n x 128] = A[n x 64] @ B[64 x 128]        (XW = node_feat @ Wg)
__launch_bounds__(256)
__global__ void k_gemm_xw(const float* __restrict__ A, const float* __restrict__ B,
                          float* __restrict__ C, int n) {
    __shared__ float As[64][64];
    __shared__ float Bs[64][128];
    int tid = threadIdx.x;
    int row0 = blockIdx.x * 64;
    const float4* A4 = (const float4*)A;
    for (int q = tid; q < 64 * 16; q += 256) {
        int r = q >> 4, c4 = q & 15;
        float4 v = make_float4(0.f, 0.f, 0.f, 0.f);
        int row = row0 + r;
        if (row < n) v = A4[(size_t)row * 16 + c4];
        *((float4*)&As[r][c4 * 4]) = v;
    }
    const float4* B4 = (const float4*)B;
    for (int q = tid; q < 64 * 32; q += 256) {
        int r = q >> 5, c4 = q & 31;
        *((float4*)&Bs[r][c4 * 4]) = B4[(size_t)r * 32 + c4];
    }
    __syncthreads();
    int cg = tid & 31, rg = tid >> 5;     // 32 col-groups x 8 row-groups
    float acc[8][4] = {};
    for (int k = 0; k < 64; ++k) {
        float4 b = *((const float4*)&Bs[k][cg * 4]);
        #pragma unroll
        for (int r = 0; r < 8; ++r) {
            float a = As[rg * 8 + r][k];
            acc[r][0] += a * b.x; acc[r][1] += a * b.y;
            acc[r][2] += a * b.z; acc[r][3] += a * b.w;
        }
    }
    for (int r = 0; r < 8; ++r) {
        int row = row0 + rg * 8 + r;
        if (row < n) {
            float4 v = make_float4(acc[r][0], acc[r][1], acc[r][2], acc[r][3]);
            *((float4*)&C[(size_t)row * 128 + cg * 4]) = v;
        }
    }
}

// ---------------------------------------------------------------------------
// agg[i,:] = dinv[i]^2 * XW[i,:] + bias      (self-loop term + bias)
__global__ void k_agg_init(const float* __restrict__ XW, const float* __restrict__ dinv,
                           const float* __restrict__ bias, float* __restrict__ agg, int n) {
    int gid = blockIdx.x * 256 + threadIdx.x;      // over n*32 float4s
    if (gid >= n * 32) return;
    int i = gid >> 5, c4 = gid & 31;
    float di = dinv[i]; float s = di * di;
    float4 v = ((const float4*)XW)[gid];
    float4 b = ((const float4*)bias)[c4];
    float4 o = make_float4(fmaf(s, v.x, b.x), fmaf(s, v.y, b.y),
                           fmaf(s, v.z, b.z), fmaf(s, v.w, b.w));
    ((float4*)agg)[gid] = o;
}

// one wavefront (64 lanes) per edge; 2 cols per lane
__global__ void k_agg_edges(const long long* ei64, const int* ei32, const int* flag,
                            const float* __restrict__ ew, const float* __restrict__ dinv,
                            const float* __restrict__ XW, float* __restrict__ agg, int E_) {
    int e = (blockIdx.x * 256 + threadIdx.x) >> 6;
    int lane = threadIdx.x & 63;
    if (e >= E_) return;
    int f = *flag;
    int s = load_idx(ei64, ei32, f, e);
    int d = load_idx(ei64, ei32, f, (size_t)E_ + e);
    float w = dinv[s] * ew[e] * dinv[d];
    const float* xs = XW + (size_t)s * 128;
    float* ad = agg + (size_t)d * 128;
    atomicAdd(&ad[lane],      w * xs[lane]);
    atomicAdd(&ad[lane + 64], w * xs[lane + 64]);
}

// ---------------------------------------------------------------------------
// C = act( A1 @ B1 + A2 @ B2 + bias ), A*: [n x 128], B*: [128 x 128]
// mode 0: Out = sigmoid(pre)                                  (Z)
// mode 1: Out = H[i,j] * sigmoid(pre)                         (H*R)
// mode 2: Out = Z[i,j]*H[i,j] + (1-Z[i,j])*tanh(pre)          (H_new, in-place over Z)
__launch_bounds__(256)
__global__ void k_gate_gemm(const float* __restrict__ A1, const float* __restrict__ B1,
                            const float* __restrict__ A2, const float* __restrict__ B2,
                            const float* __restrict__ bias,
                            const float* __restrict__ Hptr, const float* __restrict__ Zptr,
                            float* __restrict__ Out, int n, int mode) {
    __shared__ float As[64][64];
    __shared__ float Bs[64][128];
    int tid = threadIdx.x;
    int row0 = blockIdx.x * 64;
    int cg = tid & 31, rg = tid >> 5;
    float acc[8][4] = {};
    for (int ph = 0; ph < 4; ++ph) {
        const float* A = (ph < 2) ? A1 : A2;
        const float* B = (ph < 2) ? B1 : B2;
        int kb = (ph & 1) * 64;
        const float4* A4 = (const float4*)A;
        for (int q = tid; q < 64 * 16; q += 256) {
            int r = q >> 4, c4 = q & 15;
            float4 v = make_float4(0.f, 0.f, 0.f, 0.f);
            int row = row0 + r;
            if (row < n) v = A4[(size_t)row * 32 + (kb >> 2) + c4];
            *((float4*)&As[r][c4 * 4]) = v;
        }
        const float4* B4 = (const float4*)B;
        for (int q = tid; q < 64 * 32; q += 256) {
            int r = q >> 5, c4 = q & 31;
            *((float4*)&Bs[r][c4 * 4]) = B4[(size_t)(kb + r) * 32 + c4];
        }
        __syncthreads();
        for (int k = 0; k < 64; ++k) {
            float4 b = *((const float4*)&Bs[k][cg * 4]);
            #pragma unroll
            for (int r = 0; r < 8; ++r) {
                float a = As[rg * 8 + r][k];
                acc[r][0] += a * b.x; acc[r][1] += a * b.y;
                acc[r][2] += a * b.z; acc[r][3] += a * b.w;
            }
        }
        __syncthreads();
    }
    float4 bv = ((const float4*)bias)[cg];
    for (int r = 0; r < 8; ++r) {
        int row = row0 + rg * 8 + r;
        if (row >= n) continue;
        size_t base = (size_t)row * 128 + cg * 4;
        float pre[4] = { acc[r][0] + bv.x, acc[r][1] + bv.y,
                         acc[r][2] + bv.z, acc[r][3] + bv.w };
        float4 o;
        if (mode == 0) {
            o.x = 1.f / (1.f + expf(-pre[0]));
            o.y = 1.f / (1.f + expf(-pre[1]));
            o.z = 1.f / (1.f + expf(-pre[2]));
            o.w = 1.f / (1.f + expf(-pre[3]));
        } else if (mode == 1) {
            float4 h = *((const float4*)&Hptr[base]);
            o.x = h.x / (1.f + expf(-pre[0]));
            o.y = h.y / (1.f + expf(-pre[1]));
            o.z = h.z / (1.f + expf(-pre[2]));
            o.w = h.w / (1.f + expf(-pre[3]));
        } else {
            float4 h = *((const float4*)&Hptr[base]);
            float4 z = *((const float4*)&Zptr[base]);
            o.x = z.x * h.x + (1.f - z.x) * tanhf(pre[0]);
            o.y = z.y * h.y + (1.f - z.y) * tanhf(pre[1]);
            o.z = z.z * h.z + (1.f - z.z) * tanhf(pre[2]);
            o.w = z.w * h.w + (1.f - z.w) * tanhf(pre[3]);
        }
        *((float4*)&Out[base]) = o;
    }
}

// ---------------------------------------------------------------------------
// Y[n x 64] = relu(Hn[n x 128]) @ W[128 x 64] + bias
__launch_bounds__(256)
__global__ void k_head(const float* __restrict__ Hn, const float* __restrict__ W,
                       const float* __restrict__ bias, float* __restrict__ Y, int n) {
    __shared__ float As[16][128];
    int tid = threadIdx.x;
    int row0 = blockIdx.x * 16;
    const float4* H4 = (const float4*)Hn;
    for (int q = tid; q < 16 * 32; q += 256) {
        int r = q >> 5, c4 = q & 31;
        float4 v = make_float4(0.f, 0.f, 0.f, 0.f);
        int row = row0 + r;
        if (row < n) v = H4[(size_t)row * 32 + c4];
        v.x = fmaxf(v.x, 0.f); v.y = fmaxf(v.y, 0.f);
        v.z = fmaxf(v.z, 0.f); v.w = fmaxf(v.w, 0.f);
        *((float4*)&As[r][c4 * 4]) = v;
    }
    __syncthreads();
    int col = tid & 63, rsub = tid >> 6;   // 4 row-subgroups
    float acc[4] = {};
    for (int k = 0; k < 128; ++k) {
        float w = W[k * 64 + col];
        #pragma unroll
        for (int r = 0; r < 4; ++r)
            acc[r] += As[rsub + r * 4][k] * w;
    }
    for (int r = 0; r < 4; ++r) {
        int row = row0 + rsub + r * 4;
        if (row < n) Y[(size_t)row * 64 + col] = acc[r] + bias[col];
    }
}

// ---------------------------------------------------------------------------
extern "C" void kernel_launch(void* const* d_in, const int* in_sizes, int n_in,
                              void* d_out, int out_size, void* d_ws, size_t ws_size,
                              hipStream_t stream) {
    const float* node_feat   = (const float*)d_in[0];
    const float* edge_weight = (const float*)d_in[1];
    const float* H           = (const float*)d_in[2];
    const void*  ei          = d_in[3];
    const float* Wz   = (const float*)d_in[4];  const float* bz = (const float*)d_in[5];
    const float* Wr   = (const float*)d_in[6];  const float* br = (const float*)d_in[7];
    const float* Wh   = (const float*)d_in[8];  const float* bh = (const float*)d_in[9];
    const float* Wlz  = (const float*)d_in[10]; const float* blz = (const float*)d_in[11];
    const float* Wlr  = (const float*)d_in[12]; const float* blr = (const float*)d_in[13];
    const float* Wlh  = (const float*)d_in[14]; const float* blh = (const float*)d_in[15];
    const float* Whead = (const float*)d_in[16]; const float* bhead = (const float*)d_in[17];

    const int N = in_sizes[0] / F;    // 100000
    const int E = in_sizes[1];        // 1600000

    float* ws  = (float*)d_ws;
    float* deg = ws;                                  // N floats; becomes dinv in place
    int*   flag = (int*)(ws + N);
    size_t off = (((size_t)N + 64) + 255) & ~(size_t)255;
    float* XW  = ws + off;                            // N*128
    float* agg = XW + (size_t)N * HID;                // N*128
    float* HR  = agg + (size_t)N * HID;               // N*128

    float* Y  = (float*)d_out;                        // N*64
    float* Hn = Y + (size_t)N * F;                    // N*128: holds Z, then H_new

    const long long* ei64 = (const long long*)ei;
    const int*       ei32 = (const int*)ei;

    k_detect<<<1, 256, 0, stream>>>((const unsigned long long*)ei, 1024,
                                    (unsigned long long)N, flag);
    k_deg_init<<<(N + 255) / 256, 256, 0, stream>>>(deg, N);
    k_deg_acc<<<(E + 255) / 256, 256, 0, stream>>>(ei64, ei32, flag, edge_weight, deg, E);
    k_dinv<<<(N + 255) / 256, 256, 0, stream>>>(deg, N);

    const int gemmBlocks    = (N + 63) / 64;
    const int aggInitBlocks = (N * 32 + 255) / 256;
    const int aggEdgeBlocks = (E + 3) / 4;

    // gate z -> Z stored in d_out's H_new region (Hn)
    k_gemm_xw<<<gemmBlocks, 256, 0, stream>>>(node_feat, Wz, XW, N);
    k_agg_init<<<aggInitBlocks, 256, 0, stream>>>(XW, deg, bz, agg, N);
    k_agg_edges<<<aggEdgeBlocks, 256, 0, stream>>>(ei64, ei32, flag, edge_weight, deg, XW, agg, E);
    k_gate_gemm<<<gemmBlocks, 256, 0, stream>>>(agg, Wlz, H, Wlz + 128 * 128, blz,
                                                H, nullptr, Hn, N, 0);
    // gate r -> HR = H * sigmoid(pre)
    k_gemm_xw<<<gemmBlocks, 256, 0, stream>>>(node_feat, Wr, XW, N);
    k_agg_init<<<aggInitBlocks, 256, 0, stream>>>(XW, deg, br, agg, N);
    k_agg_edges<<<aggEdgeBlocks, 256, 0, stream>>>(ei64, ei32, flag, edge_weight, deg, XW, agg, E);
    k_gate_gemm<<<gemmBlocks, 256, 0, stream>>>(agg, Wlr, H, Wlr + 128 * 128, blr,
                                                H, nullptr, HR, N, 1);
    // gate h -> H_new = Z*H + (1-Z)*tanh(pre), overwrites Z in Hn
    k_gemm_xw<<<gemmBlocks, 256, 0, stream>>>(node_feat, Wh, XW, N);
    k_agg_init<<<aggInitBlocks, 256, 0, stream>>>(XW, deg, bh, agg, N);
    k_agg_edges<<<aggEdgeBlocks, 256, 0, stream>>>(ei64, ei32, flag, edge_weight, deg, XW, agg, E);
    k_gate_gemm<<<gemmBlocks, 256, 0, stream>>>(agg, Wlh, HR, Wlh + 128 * 128, blh,
                                                H, Hn, Hn, N, 2);
    // head
    k_head<<<(N + 15) / 16, 256, 0, stream>>>(Hn, Whead, bhead, Y, N);
}

// Round 2
// 791.407 us; speedup vs baseline: 3.2659x; 3.2659x over previous
//
#include <hip/hip_runtime.h>
#include <math.h>

#define F 64
#define HID 128

// ---------------------------------------------------------------------------
// index-width detection: reference declares int64, but the harness/JAX may
// deliver int32. Read first 1024 words as u64: true-int64 values are all < N;
// int32 data packed into u64 is >= 2^32 with overwhelming probability.
__global__ void k_detect(const unsigned long long* p, int n, unsigned long long Nv, int* flag) {
    __shared__ int bad;
    if (threadIdx.x == 0) bad = 0;
    __syncthreads();
    for (int i = threadIdx.x; i < n; i += blockDim.x)
        if (p[i] >= Nv) bad = 1;
    __syncthreads();
    if (threadIdx.x == 0) *flag = bad ? 0 : 1;   // 1 = int64, 0 = int32
}

__device__ __forceinline__ int load_idx(const long long* e64, const int* e32, int f, size_t pos) {
    return f ? (int)e64[pos] : e32[pos];
}

// ---------------------------------------------------------------------------
__global__ void k_deg_init(float* deg, int n) {
    int i = blockIdx.x * 256 + threadIdx.x;
    if (i < n) deg[i] = 1.0f;               // self-loop weight
}

__global__ void k_deg_acc(const long long* ei64, const int* ei32, const int* flag,
                          const float* __restrict__ ew, float* deg, int E_) {
    int e = blockIdx.x * 256 + threadIdx.x;
    if (e >= E_) return;
    int f = *flag;
    int d = load_idx(ei64, ei32, f, (size_t)E_ + e);
    atomicAdd(&deg[d], ew[e]);
}

__global__ void k_dinv(float* deg, int n) {
    int i = blockIdx.x * 256 + threadIdx.x;
    if (i < n) { float v = deg[i]; deg[i] = v > 0.f ? rsqrtf(v) : 0.f; }
}

// ---------------------------------------------------------------------------
// Combined gate weights: Wc[64x128] = Wg[64x128] @ Wl_top[128x128],
// bc[128] = blg + bg @ Wl_top.   (Wl is [256x128] row-major; top = rows 0..127)
__global__ void k_combine(const float* __restrict__ Wg, const float* __restrict__ Wl,
                          const float* __restrict__ bg, const float* __restrict__ blg,
                          float* __restrict__ Wc, float* __restrict__ bc) {
    int o = blockIdx.x * 512 + threadIdx.x;        // grid 16 x 256, 2 outputs/thread
    #pragma unroll
    for (int t = 0; t < 2; ++t, o += 256) {
        int r = o >> 7, j = o & 127;
        float s = 0.f;
        for (int k = 0; k < 128; ++k) s = fmaf(Wg[r * 128 + k], Wl[k * 128 + j], s);
        Wc[o] = s;
    }
    if (blockIdx.x == 0 && threadIdx.x < 128) {
        int j = threadIdx.x;
        float s = blg[j];
        for (int k = 0; k < 128; ++k) s = fmaf(bg[k], Wl[k * 128 + j], s);
        bc[j] = s;
    }
}

// ---------------------------------------------------------------------------
// AX[i,:] = dinv[i]^2 * X[i,:]   (self-loop contribution of A_hat @ X)
__global__ void k_ax_init(const float* __restrict__ X, const float* __restrict__ dinv,
                          float* __restrict__ AX, int n) {
    int gid = blockIdx.x * 256 + threadIdx.x;      // over n*16 float4s
    if (gid >= n * 16) return;
    int i = gid >> 4;
    float di = dinv[i]; float s = di * di;
    float4 v = ((const float4*)X)[gid];
    ((float4*)AX)[gid] = make_float4(s * v.x, s * v.y, s * v.z, s * v.w);
}

// one wavefront per edge, 1 col per lane: AX[d,:] += w * X[s,:]
__global__ void k_ax_edges(const long long* ei64, const int* ei32, const int* flag,
                           const float* __restrict__ ew, const float* __restrict__ dinv,
                           const float* __restrict__ X, float* __restrict__ AX, int E_) {
    int e = (blockIdx.x * 256 + threadIdx.x) >> 6;
    int lane = threadIdx.x & 63;
    if (e >= E_) return;
    int f = *flag;
    int s = load_idx(ei64, ei32, f, e);
    int d = load_idx(ei64, ei32, f, (size_t)E_ + e);
    float w = dinv[s] * ew[e] * dinv[d];
    atomicAdd(&AX[(size_t)d * 64 + lane], w * X[(size_t)s * 64 + lane]);
}

// ---------------------------------------------------------------------------
// pre = AX @ Wc + A2 @ B2 + bias   (K = 64 + 128 = 192)
// mode 0: Out = sigmoid(pre)                                  (Z)
// mode 1: Out = H[i,j] * sigmoid(pre)                         (H*R)
// mode 2: Out = Z[i,j]*H[i,j] + (1-Z[i,j])*tanh(pre)          (H_new, in-place over Z)
__launch_bounds__(256)
__global__ void k_gate_gemm(const float* __restrict__ AX, const float* __restrict__ Wc,
                            const float* __restrict__ A2, const float* __restrict__ B2,
                            const float* __restrict__ bias,
                            const float* __restrict__ Hptr, const float* __restrict__ Zptr,
                            float* __restrict__ Out, int n, int mode) {
    __shared__ float As[64][64];
    __shared__ float Bs[64][128];
    int tid = threadIdx.x;
    int row0 = blockIdx.x * 64;
    int cg = tid & 31, rg = tid >> 5;
    float acc[8][4] = {};
    for (int ph = 0; ph < 3; ++ph) {
        const float* A = (ph == 0) ? AX : A2;
        int ldA4 = (ph == 0) ? 16 : 32;            // float4s per row
        int kb4  = (ph == 2) ? 16 : 0;             // float4 col offset
        const float* B = (ph == 0) ? Wc : (B2 + (ph == 2 ? 64 * 128 : 0));
        const float4* A4 = (const float4*)A;
        for (int q = tid; q < 64 * 16; q += 256) {
            int r = q >> 4, c4 = q & 15;
            float4 v = make_float4(0.f, 0.f, 0.f, 0.f);
            int row = row0 + r;
            if (row < n) v = A4[(size_t)row * ldA4 + kb4 + c4];
            *((float4*)&As[r][c4 * 4]) = v;
        }
        const float4* B4 = (const float4*)B;
        for (int q = tid; q < 64 * 32; q += 256) {
            int r = q >> 5, c4 = q & 31;
            *((float4*)&Bs[r][c4 * 4]) = B4[(size_t)r * 32 + c4];
        }
        __syncthreads();
        for (int k = 0; k < 64; ++k) {
            float4 b = *((const float4*)&Bs[k][cg * 4]);
            #pragma unroll
            for (int r = 0; r < 8; ++r) {
                float a = As[rg * 8 + r][k];
                acc[r][0] += a * b.x; acc[r][1] += a * b.y;
                acc[r][2] += a * b.z; acc[r][3] += a * b.w;
            }
        }
        __syncthreads();
    }
    float4 bv = ((const float4*)bias)[cg];
    for (int r = 0; r < 8; ++r) {
        int row = row0 + rg * 8 + r;
        if (row >= n) continue;
        size_t base = (size_t)row * 128 + cg * 4;
        float pre[4] = { acc[r][0] + bv.x, acc[r][1] + bv.y,
                         acc[r][2] + bv.z, acc[r][3] + bv.w };
        float4 o;
        if (mode == 0) {
            o.x = 1.f / (1.f + expf(-pre[0]));
            o.y = 1.f / (1.f + expf(-pre[1]));
            o.z = 1.f / (1.f + expf(-pre[2]));
            o.w = 1.f / (1.f + expf(-pre[3]));
        } else if (mode == 1) {
            float4 h = *((const float4*)&Hptr[base]);
            o.x = h.x / (1.f + expf(-pre[0]));
            o.y = h.y / (1.f + expf(-pre[1]));
            o.z = h.z / (1.f + expf(-pre[2]));
            o.w = h.w / (1.f + expf(-pre[3]));
        } else {
            float4 h = *((const float4*)&Hptr[base]);
            float4 z = *((const float4*)&Zptr[base]);
            o.x = z.x * h.x + (1.f - z.x) * tanhf(pre[0]);
            o.y = z.y * h.y + (1.f - z.y) * tanhf(pre[1]);
            o.z = z.z * h.z + (1.f - z.z) * tanhf(pre[2]);
            o.w = z.w * h.w + (1.f - z.w) * tanhf(pre[3]);
        }
        *((float4*)&Out[base]) = o;
    }
}

// ---------------------------------------------------------------------------
// Y[n x 64] = relu(Hn[n x 128]) @ W[128 x 64] + bias
__launch_bounds__(256)
__global__ void k_head(const float* __restrict__ Hn, const float* __restrict__ W,
                       const float* __restrict__ bias, float* __restrict__ Y, int n) {
    __shared__ float As[16][128];
    int tid = threadIdx.x;
    int row0 = blockIdx.x * 16;
    const float4* H4 = (const float4*)Hn;
    for (int q = tid; q < 16 * 32; q += 256) {
        int r = q >> 5, c4 = q & 31;
        float4 v = make_float4(0.f, 0.f, 0.f, 0.f);
        int row = row0 + r;
        if (row < n) v = H4[(size_t)row * 32 + c4];
        v.x = fmaxf(v.x, 0.f); v.y = fmaxf(v.y, 0.f);
        v.z = fmaxf(v.z, 0.f); v.w = fmaxf(v.w, 0.f);
        *((float4*)&As[r][c4 * 4]) = v;
    }
    __syncthreads();
    int col = tid & 63, rsub = tid >> 6;   // 4 row-subgroups
    float acc[4] = {};
    for (int k = 0; k < 128; ++k) {
        float w = W[k * 64 + col];
        #pragma unroll
        for (int r = 0; r < 4; ++r)
            acc[r] += As[rsub + r * 4][k] * w;
    }
    for (int r = 0; r < 4; ++r) {
        int row = row0 + rsub + r * 4;
        if (row < n) Y[(size_t)row * 64 + col] = acc[r] + bias[col];
    }
}

// ---------------------------------------------------------------------------
extern "C" void kernel_launch(void* const* d_in, const int* in_sizes, int n_in,
                              void* d_out, int out_size, void* d_ws, size_t ws_size,
                              hipStream_t stream) {
    const float* node_feat   = (const float*)d_in[0];
    const float* edge_weight = (const float*)d_in[1];
    const float* H           = (const float*)d_in[2];
    const void*  ei          = d_in[3];
    const float* Wz   = (const float*)d_in[4];  const float* bz = (const float*)d_in[5];
    const float* Wr   = (const float*)d_in[6];  const float* br = (const float*)d_in[7];
    const float* Wh   = (const float*)d_in[8];  const float* bh = (const float*)d_in[9];
    const float* Wlz  = (const float*)d_in[10]; const float* blz = (const float*)d_in[11];
    const float* Wlr  = (const float*)d_in[12]; const float* blr = (const float*)d_in[13];
    const float* Wlh  = (const float*)d_in[14]; const float* blh = (const float*)d_in[15];
    const float* Whead = (const float*)d_in[16]; const float* bhead = (const float*)d_in[17];

    const int N = in_sizes[0] / F;    // 100000
    const int E = in_sizes[1];        // 1600000

    float* ws  = (float*)d_ws;
    float* deg = ws;                                  // N floats; becomes dinv in place
    int*   flag = (int*)(ws + N);
    float* Wc  = ws + N + 64;                         // 3 x 64*128 combined gate weights
    float* bc  = Wc + 3 * 64 * 128;                   // 3 x 128 combined biases
    float* AX  = bc + 3 * 128;                        // N*64  = A_hat @ X
    float* HR  = AX + (size_t)N * F;                  // N*128 = H * R

    float* Y  = (float*)d_out;                        // N*64
    float* Hn = Y + (size_t)N * F;                    // N*128: holds Z, then H_new

    const long long* ei64 = (const long long*)ei;
    const int*       ei32 = (const int*)ei;

    k_detect<<<1, 256, 0, stream>>>((const unsigned long long*)ei, 1024,
                                    (unsigned long long)N, flag);
    k_deg_init<<<(N + 255) / 256, 256, 0, stream>>>(deg, N);
    k_deg_acc<<<(E + 255) / 256, 256, 0, stream>>>(ei64, ei32, flag, edge_weight, deg, E);
    k_dinv<<<(N + 255) / 256, 256, 0, stream>>>(deg, N);

    // combined per-gate weights (GCN weight folded into gate GEMM's top half)
    k_combine<<<16, 256, 0, stream>>>(Wz, Wlz, bz, blz, Wc,               bc);
    k_combine<<<16, 256, 0, stream>>>(Wr, Wlr, br, blr, Wc + 64 * 128,     bc + 128);
    k_combine<<<16, 256, 0, stream>>>(Wh, Wlh, bh, blh, Wc + 2 * 64 * 128, bc + 256);

    // AX = A_hat @ X  (single aggregation over raw 64-col features)
    k_ax_init<<<(N * 16 + 255) / 256, 256, 0, stream>>>(node_feat, deg, AX, N);
    k_ax_edges<<<(E + 3) / 4, 256, 0, stream>>>(ei64, ei32, flag, edge_weight, deg,
                                                node_feat, AX, E);

    const int gemmBlocks = (N + 63) / 64;
    // gate z -> Z stored in d_out's H_new region (Hn)
    k_gate_gemm<<<gemmBlocks, 256, 0, stream>>>(AX, Wc, H, Wlz + 128 * 128, bc,
                                                H, nullptr, Hn, N, 0);
    // gate r -> HR = H * sigmoid(pre)
    k_gate_gemm<<<gemmBlocks, 256, 0, stream>>>(AX, Wc + 64 * 128, H, Wlr + 128 * 128,
                                                bc + 128, H, nullptr, HR, N, 1);
    // gate h -> H_new = Z*H + (1-Z)*tanh(pre), overwrites Z in Hn
    k_gate_gemm<<<gemmBlocks, 256, 0, stream>>>(AX, Wc + 2 * 64 * 128, HR, Wlh + 128 * 128,
                                                bc + 256, H, Hn, Hn, N, 2);
    // head
    k_head<<<(N + 15) / 16, 256, 0, stream>>>(Hn, Whead, bhead, Y, N);
}

// Round 3
// 703.707 us; speedup vs baseline: 3.6730x; 1.1246x over previous
//
#include <hip/hip_runtime.h>
#include <math.h>

#define F 64
#define HID 128

// ---------------------------------------------------------------------------
// index-width detection: reference declares int64, but the harness/JAX may
// deliver int32. Read first 1024 words as u64: true-int64 values are all < N;
// int32 data packed into u64 is >= 2^32 with overwhelming probability.
__global__ void k_detect(const unsigned long long* p, int n, unsigned long long Nv, int* flag) {
    __shared__ int bad;
    if (threadIdx.x == 0) bad = 0;
    __syncthreads();
    for (int i = threadIdx.x; i < n; i += blockDim.x)
        if (p[i] >= Nv) bad = 1;
    __syncthreads();
    if (threadIdx.x == 0) *flag = bad ? 0 : 1;   // 1 = int64, 0 = int32
}

__device__ __forceinline__ int load_idx(const long long* e64, const int* e32, int f, size_t pos) {
    return f ? (int)e64[pos] : e32[pos];
}

// ---------------------------------------------------------------------------
__global__ void k_init(float* deg, int* cnt, int n) {
    int i = blockIdx.x * 256 + threadIdx.x;
    if (i < n) { deg[i] = 1.0f; cnt[i] = 0; }     // deg starts at self-loop weight
}

// histogram of dst + weighted degree, one pass over edges
__global__ void k_hist_deg(const long long* ei64, const int* ei32, const int* flag,
                           const float* __restrict__ ew, int* cnt, float* deg, int E_) {
    int e = blockIdx.x * 256 + threadIdx.x;
    if (e >= E_) return;
    int f = *flag;
    int d = load_idx(ei64, ei32, f, (size_t)E_ + e);
    atomicAdd(&cnt[d], 1);
    atomicAdd(&deg[d], ew[e]);
}

__global__ void k_dinv(float* deg, int n) {
    int i = blockIdx.x * 256 + threadIdx.x;
    if (i < n) { float v = deg[i]; deg[i] = v > 0.f ? rsqrtf(v) : 0.f; }
}

// ---------------------------------------------------------------------------
// two-level exclusive scan of cnt[n] -> rowptr[n+1] (+ cursor copy)
// chunk = 1024 elements per block (256 threads x 4)
__global__ void k_scanA(const int* __restrict__ cnt, int* __restrict__ bsum, int n) {
    __shared__ int part[256];
    int tid = threadIdx.x;
    int base = blockIdx.x * 1024 + tid * 4;
    int s = 0;
    #pragma unroll
    for (int t = 0; t < 4; ++t) { int i = base + t; if (i < n) s += cnt[i]; }
    part[tid] = s; __syncthreads();
    for (int off = 128; off > 0; off >>= 1) {
        if (tid < off) part[tid] += part[tid + off];
        __syncthreads();
    }
    if (tid == 0) bsum[blockIdx.x] = part[0];
}

__global__ void k_scanB(int* bsum, int nb) {        // nb <= 256
    __shared__ int sh[256];
    int tid = threadIdx.x;
    int v = (tid < nb) ? bsum[tid] : 0;
    sh[tid] = v; __syncthreads();
    for (int off = 1; off < 256; off <<= 1) {
        int t = (tid >= off) ? sh[tid - off] : 0;
        __syncthreads();
        sh[tid] += t;
        __syncthreads();
    }
    if (tid < nb) bsum[tid] = sh[tid] - v;          // exclusive
}

__global__ void k_scanC(const int* __restrict__ cnt, const int* __restrict__ bsum,
                        int* __restrict__ rowptr, int* __restrict__ cursor, int n, int E_) {
    __shared__ int part[256];
    int tid = threadIdx.x;
    int base = blockIdx.x * 1024;
    int loc[4]; int s = 0;
    #pragma unroll
    for (int t = 0; t < 4; ++t) {
        int i = base + tid * 4 + t;
        int c = (i < n) ? cnt[i] : 0;
        loc[t] = s; s += c;
    }
    part[tid] = s; __syncthreads();
    int mysum = s;
    for (int off = 1; off < 256; off <<= 1) {
        int t = (tid >= off) ? part[tid - off] : 0;
        __syncthreads();
        part[tid] += t;
        __syncthreads();
    }
    int thbase = bsum[blockIdx.x] + part[tid] - mysum;   // exclusive base for this thread
    #pragma unroll
    for (int t = 0; t < 4; ++t) {
        int i = base + tid * 4 + t;
        if (i < n) { int v = thbase + loc[t]; rowptr[i] = v; cursor[i] = v; }
    }
    if (blockIdx.x == 0 && tid == 0) rowptr[n] = E_;
}

// ---------------------------------------------------------------------------
// scatter edges into CSR order: csr[pos] = (src, w), w = dinv[s]*ew*dinv[d]
__global__ void k_scatter(const long long* ei64, const int* ei32, const int* flag,
                          const float* __restrict__ ew, const float* __restrict__ dinv,
                          int* cursor, int2* __restrict__ csr, int E_) {
    int e = blockIdx.x * 256 + threadIdx.x;
    if (e >= E_) return;
    int f = *flag;
    int s = load_idx(ei64, ei32, f, e);
    int d = load_idx(ei64, ei32, f, (size_t)E_ + e);
    float w = dinv[s] * ew[e] * dinv[d];
    int pos = atomicAdd(&cursor[d], 1);
    csr[pos] = make_int2(s, __float_as_int(w));
}

// ---------------------------------------------------------------------------
// AX[i,:] = dinv[i]^2 * X[i,:] + sum_{e in row i} w_e * X[src_e,:]
// one wave per node, lane = column; no atomics
__launch_bounds__(256)
__global__ void k_spmm(const int2* __restrict__ csr, const int* __restrict__ rowptr,
                       const float* __restrict__ dinv, const float* __restrict__ X,
                       float* __restrict__ AX, int n) {
    int node = blockIdx.x * 4 + (threadIdx.x >> 6);
    int lane = threadIdx.x & 63;
    if (node >= n) return;
    float di = dinv[node];
    float acc = di * di * X[(size_t)node * 64 + lane];
    int beg = rowptr[node], end = rowptr[node + 1];
    for (int j = beg; j < end; ++j) {
        int2 e = csr[j];
        acc = fmaf(__int_as_float(e.y), X[(size_t)e.x * 64 + lane], acc);
    }
    AX[(size_t)node * 64 + lane] = acc;
}

// ---------------------------------------------------------------------------
// Combined gate weights: Wc[64x128] = Wg[64x128] @ Wl_top[128x128],
// bc[128] = blg + bg @ Wl_top.   (Wl is [256x128] row-major; top = rows 0..127)
__global__ void k_combine(const float* __restrict__ Wg, const float* __restrict__ Wl,
                          const float* __restrict__ bg, const float* __restrict__ blg,
                          float* __restrict__ Wc, float* __restrict__ bc) {
    int o = blockIdx.x * 512 + threadIdx.x;        // grid 16 x 256, 2 outputs/thread
    #pragma unroll
    for (int t = 0; t < 2; ++t, o += 256) {
        int r = o >> 7, j = o & 127;
        float s = 0.f;
        for (int k = 0; k < 128; ++k) s = fmaf(Wg[r * 128 + k], Wl[k * 128 + j], s);
        Wc[o] = s;
    }
    if (blockIdx.x == 0 && threadIdx.x < 128) {
        int j = threadIdx.x;
        float s = blg[j];
        for (int k = 0; k < 128; ++k) s = fmaf(bg[k], Wl[k * 128 + j], s);
        bc[j] = s;
    }
}

// ---------------------------------------------------------------------------
// Fused Z+R gate GEMM.  K = 64 (AX) + 128 (H).
// pre_g = AX @ Wc_g + H @ Wl_g_bot + bc_g  (g in {z,r})
// Z  = sigmoid(pre_z)          -> Zout
// HR = H * sigmoid(pre_r)      -> HRout
__launch_bounds__(256)
__global__ void k_gate_zr(const float* __restrict__ AX, const float* __restrict__ Hm,
                          const float* __restrict__ Wcz, const float* __restrict__ Wcr,
                          const float* __restrict__ Bz2, const float* __restrict__ Br2,
                          const float* __restrict__ bcz, const float* __restrict__ bcr,
                          float* __restrict__ Zout, float* __restrict__ HRout, int n) {
    __shared__ float As[64][64];
    __shared__ float Bs[64][128];
    int tid = threadIdx.x;
    int row0 = blockIdx.x * 64;
    int cg = tid & 31, rg = tid >> 5;
    float accz[8][4] = {}, accr[8][4] = {};
    for (int ph = 0; ph < 3; ++ph) {
        const float* A = (ph == 0) ? AX : Hm;
        int ldA4 = (ph == 0) ? 16 : 32;
        int kb4  = (ph == 2) ? 16 : 0;
        const float4* A4 = (const float4*)A;
        for (int q = tid; q < 64 * 16; q += 256) {
            int r = q >> 4, c4 = q & 15;
            float4 v = make_float4(0.f, 0.f, 0.f, 0.f);
            int row = row0 + r;
            if (row < n) v = A4[(size_t)row * ldA4 + kb4 + c4];
            *((float4*)&As[r][c4 * 4]) = v;
        }
        // --- B for z ---
        {
            const float* B = (ph == 0) ? Wcz : (Bz2 + (ph == 2 ? 64 * 128 : 0));
            const float4* B4 = (const float4*)B;
            for (int q = tid; q < 64 * 32; q += 256) {
                int r = q >> 5, c4 = q & 31;
                *((float4*)&Bs[r][c4 * 4]) = B4[(size_t)r * 32 + c4];
            }
        }
        __syncthreads();
        for (int k = 0; k < 64; ++k) {
            float4 b = *((const float4*)&Bs[k][cg * 4]);
            #pragma unroll
            for (int r = 0; r < 8; ++r) {
                float a = As[rg * 8 + r][k];
                accz[r][0] += a * b.x; accz[r][1] += a * b.y;
                accz[r][2] += a * b.z; accz[r][3] += a * b.w;
            }
        }
        __syncthreads();
        // --- B for r ---
        {
            const float* B = (ph == 0) ? Wcr : (Br2 + (ph == 2 ? 64 * 128 : 0));
            const float4* B4 = (const float4*)B;
            for (int q = tid; q < 64 * 32; q += 256) {
                int r = q >> 5, c4 = q & 31;
                *((float4*)&Bs[r][c4 * 4]) = B4[(size_t)r * 32 + c4];
            }
        }
        __syncthreads();
        for (int k = 0; k < 64; ++k) {
            float4 b = *((const float4*)&Bs[k][cg * 4]);
            #pragma unroll
            for (int r = 0; r < 8; ++r) {
                float a = As[rg * 8 + r][k];
                accr[r][0] += a * b.x; accr[r][1] += a * b.y;
                accr[r][2] += a * b.z; accr[r][3] += a * b.w;
            }
        }
        __syncthreads();
    }
    float4 bvz = ((const float4*)bcz)[cg];
    float4 bvr = ((const float4*)bcr)[cg];
    for (int r = 0; r < 8; ++r) {
        int row = row0 + rg * 8 + r;
        if (row >= n) continue;
        size_t base = (size_t)row * 128 + cg * 4;
        float4 oz;
        oz.x = 1.f / (1.f + expf(-(accz[r][0] + bvz.x)));
        oz.y = 1.f / (1.f + expf(-(accz[r][1] + bvz.y)));
        oz.z = 1.f / (1.f + expf(-(accz[r][2] + bvz.z)));
        oz.w = 1.f / (1.f + expf(-(accz[r][3] + bvz.w)));
        *((float4*)&Zout[base]) = oz;
        float4 h = *((const float4*)&Hm[base]);
        float4 ohr;
        ohr.x = h.x / (1.f + expf(-(accr[r][0] + bvr.x)));
        ohr.y = h.y / (1.f + expf(-(accr[r][1] + bvr.y)));
        ohr.z = h.z / (1.f + expf(-(accr[r][2] + bvr.z)));
        ohr.w = h.w / (1.f + expf(-(accr[r][3] + bvr.w)));
        *((float4*)&HRout[base]) = ohr;
    }
}

// ---------------------------------------------------------------------------
// gate h: pre = AX @ Wch + HR @ Wlh_bot + bch
// H_new = Z*H + (1-Z)*tanh(pre), overwrites Z (same-thread read/write)
__launch_bounds__(256)
__global__ void k_gate_h(const float* __restrict__ AX, const float* __restrict__ Wch,
                         const float* __restrict__ HR, const float* __restrict__ Bh2,
                         const float* __restrict__ bch,
                         const float* __restrict__ Hm, float* __restrict__ ZHn, int n) {
    __shared__ float As[64][64];
    __shared__ float Bs[64][128];
    int tid = threadIdx.x;
    int row0 = blockIdx.x * 64;
    int cg = tid & 31, rg = tid >> 5;
    float acc[8][4] = {};
    for (int ph = 0; ph < 3; ++ph) {
        const float* A = (ph == 0) ? AX : HR;
        int ldA4 = (ph == 0) ? 16 : 32;
        int kb4  = (ph == 2) ? 16 : 0;
        const float* B = (ph == 0) ? Wch : (Bh2 + (ph == 2 ? 64 * 128 : 0));
        const float4* A4 = (const float4*)A;
        for (int q = tid; q < 64 * 16; q += 256) {
            int r = q >> 4, c4 = q & 15;
            float4 v = make_float4(0.f, 0.f, 0.f, 0.f);
            int row = row0 + r;
            if (row < n) v = A4[(size_t)row * ldA4 + kb4 + c4];
            *((float4*)&As[r][c4 * 4]) = v;
        }
        const float4* B4 = (const float4*)B;
        for (int q = tid; q < 64 * 32; q += 256) {
            int r = q >> 5, c4 = q & 31;
            *((float4*)&Bs[r][c4 * 4]) = B4[(size_t)r * 32 + c4];
        }
        __syncthreads();
        for (int k = 0; k < 64; ++k) {
            float4 b = *((const float4*)&Bs[k][cg * 4]);
            #pragma unroll
            for (int r = 0; r < 8; ++r) {
                float a = As[rg * 8 + r][k];
                acc[r][0] += a * b.x; acc[r][1] += a * b.y;
                acc[r][2] += a * b.z; acc[r][3] += a * b.w;
            }
        }
        __syncthreads();
    }
    float4 bv = ((const float4*)bch)[cg];
    for (int r = 0; r < 8; ++r) {
        int row = row0 + rg * 8 + r;
        if (row >= n) continue;
        size_t base = (size_t)row * 128 + cg * 4;
        float4 h = *((const float4*)&Hm[base]);
        float4 z = *((const float4*)&ZHn[base]);
        float4 o;
        o.x = z.x * h.x + (1.f - z.x) * tanhf(acc[r][0] + bv.x);
        o.y = z.y * h.y + (1.f - z.y) * tanhf(acc[r][1] + bv.y);
        o.z = z.z * h.z + (1.f - z.z) * tanhf(acc[r][2] + bv.z);
        o.w = z.w * h.w + (1.f - z.w) * tanhf(acc[r][3] + bv.w);
        *((float4*)&ZHn[base]) = o;
    }
}

// ---------------------------------------------------------------------------
// Y[n x 64] = relu(Hn[n x 128]) @ W[128 x 64] + bias
__launch_bounds__(256)
__global__ void k_head(const float* __restrict__ Hn, const float* __restrict__ W,
                       const float* __restrict__ bias, float* __restrict__ Y, int n) {
    __shared__ float As[16][128];
    int tid = threadIdx.x;
    int row0 = blockIdx.x * 16;
    const float4* H4 = (const float4*)Hn;
    for (int q = tid; q < 16 * 32; q += 256) {
        int r = q >> 5, c4 = q & 31;
        float4 v = make_float4(0.f, 0.f, 0.f, 0.f);
        int row = row0 + r;
        if (row < n) v = H4[(size_t)row * 32 + c4];
        v.x = fmaxf(v.x, 0.f); v.y = fmaxf(v.y, 0.f);
        v.z = fmaxf(v.z, 0.f); v.w = fmaxf(v.w, 0.f);
        *((float4*)&As[r][c4 * 4]) = v;
    }
    __syncthreads();
    int col = tid & 63, rsub = tid >> 6;   // 4 row-subgroups
    float acc[4] = {};
    for (int k = 0; k < 128; ++k) {
        float w = W[k * 64 + col];
        #pragma unroll
        for (int r = 0; r < 4; ++r)
            acc[r] += As[rsub + r * 4][k] * w;
    }
    for (int r = 0; r < 4; ++r) {
        int row = row0 + rsub + r * 4;
        if (row < n) Y[(size_t)row * 64 + col] = acc[r] + bias[col];
    }
}

// ---------------------------------------------------------------------------
extern "C" void kernel_launch(void* const* d_in, const int* in_sizes, int n_in,
                              void* d_out, int out_size, void* d_ws, size_t ws_size,
                              hipStream_t stream) {
    const float* node_feat   = (const float*)d_in[0];
    const float* edge_weight = (const float*)d_in[1];
    const float* H           = (const float*)d_in[2];
    const void*  ei          = d_in[3];
    const float* Wz   = (const float*)d_in[4];  const float* bz = (const float*)d_in[5];
    const float* Wr   = (const float*)d_in[6];  const float* br = (const float*)d_in[7];
    const float* Wh   = (const float*)d_in[8];  const float* bh = (const float*)d_in[9];
    const float* Wlz  = (const float*)d_in[10]; const float* blz = (const float*)d_in[11];
    const float* Wlr  = (const float*)d_in[12]; const float* blr = (const float*)d_in[13];
    const float* Wlh  = (const float*)d_in[14]; const float* blh = (const float*)d_in[15];
    const float* Whead = (const float*)d_in[16]; const float* bhead = (const float*)d_in[17];

    const int N = in_sizes[0] / F;    // 100000
    const int E = in_sizes[1];        // 1600000
    const int NB = (N + 1023) / 1024; // scan blocks (98)

    float* ws   = (float*)d_ws;
    int*   flag = (int*)ws;                            // [64 pad]
    float* deg  = ws + 64;                             // N  (becomes dinv in place)
    int*   rowptr = (int*)(deg + N);                   // N+1
    int*   cursor = rowptr + N + 1;                    // N
    int*   cnt    = cursor + N;                        // N
    int*   bsum   = cnt + N;                           // 256
    float* Wc   = (float*)(bsum + 256);                // 3 x 64*128
    float* bc   = Wc + 3 * 64 * 128;                   // 3 x 128
    size_t csr_off = ((size_t)((bc + 3 * 128) - ws) + 1) & ~(size_t)1;  // 8B align
    int2*  csr  = (int2*)(ws + csr_off);               // E int2
    float* HR   = ws + csr_off + 2 * (size_t)E;        // N*128

    float* Y  = (float*)d_out;                         // N*64 : holds AX until k_head
    float* AX = Y;
    float* Hn = Y + (size_t)N * F;                     // N*128: holds Z, then H_new

    const long long* ei64 = (const long long*)ei;
    const int*       ei32 = (const int*)ei;

    k_detect<<<1, 256, 0, stream>>>((const unsigned long long*)ei, 1024,
                                    (unsigned long long)N, flag);
    k_init<<<(N + 255) / 256, 256, 0, stream>>>(deg, cnt, N);
    k_hist_deg<<<(E + 255) / 256, 256, 0, stream>>>(ei64, ei32, flag, edge_weight, cnt, deg, E);
    k_scanA<<<NB, 256, 0, stream>>>(cnt, bsum, N);
    k_scanB<<<1, 256, 0, stream>>>(bsum, NB);
    k_scanC<<<NB, 256, 0, stream>>>(cnt, bsum, rowptr, cursor, N, E);
    k_dinv<<<(N + 255) / 256, 256, 0, stream>>>(deg, N);
    k_scatter<<<(E + 255) / 256, 256, 0, stream>>>(ei64, ei32, flag, edge_weight, deg,
                                                   cursor, csr, E);
    k_spmm<<<(N + 3) / 4, 256, 0, stream>>>(csr, rowptr, deg, node_feat, AX, N);

    // combined per-gate weights (GCN weight folded into gate GEMM's top half)
    k_combine<<<16, 256, 0, stream>>>(Wz, Wlz, bz, blz, Wc,               bc);
    k_combine<<<16, 256, 0, stream>>>(Wr, Wlr, br, blr, Wc + 64 * 128,     bc + 128);
    k_combine<<<16, 256, 0, stream>>>(Wh, Wlh, bh, blh, Wc + 2 * 64 * 128, bc + 256);

    const int gemmBlocks = (N + 63) / 64;
    // fused z+r: Z -> Hn, HR -> ws
    k_gate_zr<<<gemmBlocks, 256, 0, stream>>>(AX, H, Wc, Wc + 64 * 128,
                                              Wlz + 128 * 128, Wlr + 128 * 128,
                                              bc, bc + 128, Hn, HR, N);
    // gate h: H_new = Z*H + (1-Z)*tanh(pre), overwrites Z in Hn
    k_gate_h<<<gemmBlocks, 256, 0, stream>>>(AX, Wc + 2 * 64 * 128, HR,
                                             Wlh + 128 * 128, bc + 256, H, Hn, N);
    // head (overwrites AX region with Y — AX is dead here)
    k_head<<<(N + 15) / 16, 256, 0, stream>>>(Hn, Whead, bhead, Y, N);
}

// Round 4
// 619.367 us; speedup vs baseline: 4.1731x; 1.1362x over previous
//
#include <hip/hip_runtime.h>
#include <math.h>

#define F 64
#define HID 128

typedef __attribute__((ext_vector_type(8))) short short8v;
typedef __attribute__((ext_vector_type(4))) float f32x4;
#define MFMA_BF16 __builtin_amdgcn_mfma_f32_16x16x32_bf16

__device__ __forceinline__ unsigned short f2bf(float f) {
    unsigned u = __float_as_uint(f);
    u = (u + 0x7FFFu + ((u >> 16) & 1u)) >> 16;      // round-to-nearest-even
    return (unsigned short)u;
}

// ---------------------------------------------------------------------------
// index-width detection: reference declares int64, but the harness/JAX may
// deliver int32. Read first 1024 words as u64: true-int64 values are all < N;
// int32 data packed into u64 is >= 2^32 with overwhelming probability.
__global__ void k_detect(const unsigned long long* p, int n, unsigned long long Nv, int* flag) {
    __shared__ int bad;
    if (threadIdx.x == 0) bad = 0;
    __syncthreads();
    for (int i = threadIdx.x; i < n; i += blockDim.x)
        if (p[i] >= Nv) bad = 1;
    __syncthreads();
    if (threadIdx.x == 0) *flag = bad ? 0 : 1;   // 1 = int64, 0 = int32
}

__device__ __forceinline__ int load_idx(const long long* e64, const int* e32, int f, size_t pos) {
    return f ? (int)e64[pos] : e32[pos];
}

// ---------------------------------------------------------------------------
__global__ void k_init(float* deg, int* cnt, int n) {
    int i = blockIdx.x * 256 + threadIdx.x;
    if (i < n) { deg[i] = 1.0f; cnt[i] = 0; }     // deg starts at self-loop weight
}

__global__ void k_hist_deg(const long long* ei64, const int* ei32, const int* flag,
                           const float* __restrict__ ew, int* cnt, float* deg, int E_) {
    int e = blockIdx.x * 256 + threadIdx.x;
    if (e >= E_) return;
    int f = *flag;
    int d = load_idx(ei64, ei32, f, (size_t)E_ + e);
    atomicAdd(&cnt[d], 1);
    atomicAdd(&deg[d], ew[e]);
}

__global__ void k_dinv(float* deg, int n) {
    int i = blockIdx.x * 256 + threadIdx.x;
    if (i < n) { float v = deg[i]; deg[i] = v > 0.f ? rsqrtf(v) : 0.f; }
}

// ---------------------------------------------------------------------------
// two-level exclusive scan of cnt[n] -> rowptr[n+1] (+ cursor copy)
__global__ void k_scanA(const int* __restrict__ cnt, int* __restrict__ bsum, int n) {
    __shared__ int part[256];
    int tid = threadIdx.x;
    int base = blockIdx.x * 1024 + tid * 4;
    int s = 0;
    #pragma unroll
    for (int t = 0; t < 4; ++t) { int i = base + t; if (i < n) s += cnt[i]; }
    part[tid] = s; __syncthreads();
    for (int off = 128; off > 0; off >>= 1) {
        if (tid < off) part[tid] += part[tid + off];
        __syncthreads();
    }
    if (tid == 0) bsum[blockIdx.x] = part[0];
}

__global__ void k_scanB(int* bsum, int nb) {        // nb <= 256
    __shared__ int sh[256];
    int tid = threadIdx.x;
    int v = (tid < nb) ? bsum[tid] : 0;
    sh[tid] = v; __syncthreads();
    for (int off = 1; off < 256; off <<= 1) {
        int t = (tid >= off) ? sh[tid - off] : 0;
        __syncthreads();
        sh[tid] += t;
        __syncthreads();
    }
    if (tid < nb) bsum[tid] = sh[tid] - v;          // exclusive
}

__global__ void k_scanC(const int* __restrict__ cnt, const int* __restrict__ bsum,
                        int* __restrict__ rowptr, int* __restrict__ cursor, int n, int E_) {
    __shared__ int part[256];
    int tid = threadIdx.x;
    int base = blockIdx.x * 1024;
    int loc[4]; int s = 0;
    #pragma unroll
    for (int t = 0; t < 4; ++t) {
        int i = base + tid * 4 + t;
        int c = (i < n) ? cnt[i] : 0;
        loc[t] = s; s += c;
    }
    part[tid] = s; __syncthreads();
    int mysum = s;
    for (int off = 1; off < 256; off <<= 1) {
        int t = (tid >= off) ? part[tid - off] : 0;
        __syncthreads();
        part[tid] += t;
        __syncthreads();
    }
    int thbase = bsum[blockIdx.x] + part[tid] - mysum;
    #pragma unroll
    for (int t = 0; t < 4; ++t) {
        int i = base + tid * 4 + t;
        if (i < n) { int v = thbase + loc[t]; rowptr[i] = v; cursor[i] = v; }
    }
    if (blockIdx.x == 0 && tid == 0) rowptr[n] = E_;
}

// ---------------------------------------------------------------------------
__global__ void k_scatter(const long long* ei64, const int* ei32, const int* flag,
                          const float* __restrict__ ew, const float* __restrict__ dinv,
                          int* cursor, int2* __restrict__ csr, int E_) {
    int e = blockIdx.x * 256 + threadIdx.x;
    if (e >= E_) return;
    int f = *flag;
    int s = load_idx(ei64, ei32, f, e);
    int d = load_idx(ei64, ei32, f, (size_t)E_ + e);
    float w = dinv[s] * ew[e] * dinv[d];
    int pos = atomicAdd(&cursor[d], 1);
    csr[pos] = make_int2(s, __float_as_int(w));
}

// ---------------------------------------------------------------------------
// AX[i,:] = dinv[i]^2 * X[i,:] + sum_{e in row i} w_e * X[src_e,:]
__launch_bounds__(256)
__global__ void k_spmm(const int2* __restrict__ csr, const int* __restrict__ rowptr,
                       const float* __restrict__ dinv, const float* __restrict__ X,
                       float* __restrict__ AX, int n) {
    int node = blockIdx.x * 4 + (threadIdx.x >> 6);
    int lane = threadIdx.x & 63;
    if (node >= n) return;
    float di = dinv[node];
    float acc = di * di * X[(size_t)node * 64 + lane];
    int beg = rowptr[node], end = rowptr[node + 1];
    for (int j = beg; j < end; ++j) {
        int2 e = csr[j];
        acc = fmaf(__int_as_float(e.y), X[(size_t)e.x * 64 + lane], acc);
    }
    AX[(size_t)node * 64 + lane] = acc;
}

// ---------------------------------------------------------------------------
// Combined gate weights: Wc[64x128] = Wg[64x128] @ Wl_top[128x128],
// bc[128] = blg + bg @ Wl_top.
__global__ void k_combine(const float* __restrict__ Wg, const float* __restrict__ Wl,
                          const float* __restrict__ bg, const float* __restrict__ blg,
                          float* __restrict__ Wc, float* __restrict__ bc) {
    int o = blockIdx.x * 512 + threadIdx.x;
    #pragma unroll
    for (int t = 0; t < 2; ++t, o += 256) {
        int r = o >> 7, j = o & 127;
        float s = 0.f;
        for (int k = 0; k < 128; ++k) s = fmaf(Wg[r * 128 + k], Wl[k * 128 + j], s);
        Wc[o] = s;
    }
    if (blockIdx.x == 0 && threadIdx.x < 128) {
        int j = threadIdx.x;
        float s = blg[j];
        for (int k = 0; k < 128; ++k) s = fmaf(bg[k], Wl[k * 128 + j], s);
        bc[j] = s;
    }
}

// ---------------------------------------------------------------------------
// Pack gate B (K=192, Ncol=128) into MFMA-fragment order, bf16.
// frag fi = nt*6+ks; element (lane,j): k = ks*32+(lane>>4)*8+j, col = nt*16+(lane&15)
// source: k<64 -> Wcg[k][col]; k>=64 -> Wl[128+(k-64)][col]
__global__ void k_pack_gate(const float* __restrict__ Wcg, const float* __restrict__ Wl,
                            short* __restrict__ out) {
    int t = blockIdx.x * 256 + threadIdx.x;     // 48*64 threads
    if (t >= 48 * 64) return;
    int fi = t >> 6, lane = t & 63;
    int nt = fi / 6, ks = fi - nt * 6;
    int col = nt * 16 + (lane & 15);
    int kb = ks * 32 + ((lane >> 4) * 8);
    short8v o;
    #pragma unroll
    for (int j = 0; j < 8; ++j) {
        int k = kb + j;
        float v = (k < 64) ? Wcg[k * 128 + col] : Wl[(64 + k) * 128 + col];
        o[j] = (short)f2bf(v);
    }
    *(short8v*)(out + (size_t)fi * 512 + lane * 8) = o;
}

// head B (K=128, Ncol=64): frag fi = nt*4+ks (nt<4, ks<4)
__global__ void k_pack_head(const float* __restrict__ Wh, short* __restrict__ out) {
    int t = blockIdx.x * 256 + threadIdx.x;     // 16*64 threads
    if (t >= 16 * 64) return;
    int fi = t >> 6, lane = t & 63;
    int nt = fi >> 2, ks = fi & 3;
    int col = nt * 16 + (lane & 15);
    int kb = ks * 32 + ((lane >> 4) * 8);
    short8v o;
    #pragma unroll
    for (int j = 0; j < 8; ++j) o[j] = (short)f2bf(Wh[(kb + j) * 64 + col]);
    *(short8v*)(out + (size_t)fi * 512 + lane * 8) = o;
}

// ---------------------------------------------------------------------------
// Fused TGCN cell: for 64 rows/block (4 waves x 16 rows, zero barriers):
//   pre_z = [AX|H] @ Bz;  Z = sigmoid(pre_z+bcz)        (Z kept in regs)
//   pre_r = [AX|H] @ Br;  HR = H * sigmoid(pre_r+bcr)   (-> LDS bf16)
//   pre_h = [AX|HR] @ Bh; Hn = Z*H + (1-Z)*tanh(pre_h+bch) (-> global)
//   Y = relu(Hn) @ Bhead + bhead                         (-> global)
__launch_bounds__(256)
__global__ void k_cell(const float* __restrict__ AXY,    // N x 64 (AX in, Y out)
                       const float* __restrict__ Hm,     // N x 128
                       const short* __restrict__ Wpk,    // 3 x 48 frags x 512
                       const short* __restrict__ Hpk,    // 16 frags x 512
                       const float* __restrict__ bc,     // 3 x 128
                       const float* __restrict__ bhead,  // 64
                       float* __restrict__ Hn,           // N x 128 out
                       float* __restrict__ Yout,         // N x 64 out (== AXY)
                       int n) {
    __shared__ short As[64 * 200];    // [row][k 0..191], stride 200 (400B: bank-stride 4)
    __shared__ short HRs[64 * 136];   // [row][k2 0..127], stride 136 (272B)
    int tid = threadIdx.x;
    int w = tid >> 6, lane = tid & 63;
    int row0 = blockIdx.x * 64;
    int rbase = row0 + w * 16;

    // ---- stage this wave's 16 rows of [AX | H] into LDS as bf16 ----
    const float4* AX4 = (const float4*)AXY;
    const float4* H4  = (const float4*)Hm;
    for (int q = lane; q < 16 * 48; q += 64) {
        int r = q / 48, c4 = q - r * 48;
        int grow = rbase + r;
        float4 v = make_float4(0.f, 0.f, 0.f, 0.f);
        if (grow < n) v = (c4 < 16) ? AX4[(size_t)grow * 16 + c4]
                                    : H4[(size_t)grow * 32 + (c4 - 16)];
        short4 s4;
        s4.x = (short)f2bf(v.x); s4.y = (short)f2bf(v.y);
        s4.z = (short)f2bf(v.z); s4.w = (short)f2bf(v.w);
        *(short4*)&As[(w * 16 + r) * 200 + c4 * 4] = s4;
    }

    int arow = w * 16 + (lane & 15);
    int kg = (lane >> 4) * 8;

    // ---- A-frags for [AX|H], K=192 (6 k-steps of 32) ----
    short8v afr[6];
    #pragma unroll
    for (int ks = 0; ks < 6; ++ks)
        afr[ks] = *(const short8v*)&As[arow * 200 + ks * 32 + kg];

    const short8v* Bz = (const short8v*)Wpk;
    const short8v* Br = (const short8v*)(Wpk + 48 * 512);
    const short8v* Bh = (const short8v*)(Wpk + 2 * 48 * 512);

    f32x4 accz[8] = {};
    f32x4 accr[8] = {};
    #pragma unroll
    for (int nt = 0; nt < 8; ++nt) {
        #pragma unroll
        for (int ks = 0; ks < 6; ++ks)
            accz[nt] = MFMA_BF16(afr[ks], Bz[(nt * 6 + ks) * 64 + lane], accz[nt], 0, 0, 0);
        #pragma unroll
        for (int ks = 0; ks < 6; ++ks)
            accr[nt] = MFMA_BF16(afr[ks], Br[(nt * 6 + ks) * 64 + lane], accr[nt], 0, 0, 0);
    }

    // ---- z/r epilogue: Z in regs (reuse accz), HR -> LDS bf16 ----
    #pragma unroll
    for (int nt = 0; nt < 8; ++nt) {
        int col = nt * 16 + (lane & 15);
        float bz = bc[col];
        float br = bc[128 + col];
        #pragma unroll
        for (int i = 0; i < 4; ++i) {
            int lrow = w * 16 + (lane >> 4) * 4 + i;
            int grow = row0 + lrow;
            float z = 1.f / (1.f + expf(-(accz[nt][i] + bz)));
            float hv = (grow < n) ? Hm[(size_t)grow * 128 + col] : 0.f;
            float hr = hv / (1.f + expf(-(accr[nt][i] + br)));
            accz[nt][i] = z;
            HRs[lrow * 136 + col] = (short)f2bf(hr);
        }
    }

    // ---- h gate: A = [AX | HR] ----
    short8v ahr[6];
    ahr[0] = afr[0]; ahr[1] = afr[1];
    #pragma unroll
    for (int ks = 0; ks < 4; ++ks)
        ahr[2 + ks] = *(const short8v*)&HRs[arow * 136 + ks * 32 + kg];

    f32x4 acch[8] = {};
    #pragma unroll
    for (int nt = 0; nt < 8; ++nt) {
        #pragma unroll
        for (int ks = 0; ks < 6; ++ks)
            acch[nt] = MFMA_BF16(ahr[ks], Bh[(nt * 6 + ks) * 64 + lane], acch[nt], 0, 0, 0);
    }

    // ---- h epilogue: Hn -> global, relu(Hn) -> LDS bf16 (reuse HRs) ----
    #pragma unroll
    for (int nt = 0; nt < 8; ++nt) {
        int col = nt * 16 + (lane & 15);
        float bh = bc[256 + col];
        #pragma unroll
        for (int i = 0; i < 4; ++i) {
            int lrow = w * 16 + (lane >> 4) * 4 + i;
            int grow = row0 + lrow;
            float th = tanhf(acch[nt][i] + bh);
            float z = accz[nt][i];
            float hv = (grow < n) ? Hm[(size_t)grow * 128 + col] : 0.f;
            float hn = z * hv + (1.f - z) * th;
            if (grow < n) Hn[(size_t)grow * 128 + col] = hn;
            HRs[lrow * 136 + col] = (short)f2bf(fmaxf(hn, 0.f));
        }
    }

    // ---- head: Y = relu(Hn) @ Bhead + bhead (K=128, 64 cols) ----
    short8v ay[4];
    #pragma unroll
    for (int ks = 0; ks < 4; ++ks)
        ay[ks] = *(const short8v*)&HRs[arow * 136 + ks * 32 + kg];
    const short8v* By = (const short8v*)Hpk;
    f32x4 accy[4] = {};
    #pragma unroll
    for (int nt = 0; nt < 4; ++nt) {
        #pragma unroll
        for (int ks = 0; ks < 4; ++ks)
            accy[nt] = MFMA_BF16(ay[ks], By[(nt * 4 + ks) * 64 + lane], accy[nt], 0, 0, 0);
    }
    #pragma unroll
    for (int nt = 0; nt < 4; ++nt) {
        int col = nt * 16 + (lane & 15);
        float by = bhead[col];
        #pragma unroll
        for (int i = 0; i < 4; ++i) {
            int grow = row0 + w * 16 + (lane >> 4) * 4 + i;
            if (grow < n) Yout[(size_t)grow * 64 + col] = accy[nt][i] + by;
        }
    }
}

// ---------------------------------------------------------------------------
extern "C" void kernel_launch(void* const* d_in, const int* in_sizes, int n_in,
                              void* d_out, int out_size, void* d_ws, size_t ws_size,
                              hipStream_t stream) {
    const float* node_feat   = (const float*)d_in[0];
    const float* edge_weight = (const float*)d_in[1];
    const float* H           = (const float*)d_in[2];
    const void*  ei          = d_in[3];
    const float* Wz   = (const float*)d_in[4];  const float* bz = (const float*)d_in[5];
    const float* Wr   = (const float*)d_in[6];  const float* br = (const float*)d_in[7];
    const float* Wh   = (const float*)d_in[8];  const float* bh = (const float*)d_in[9];
    const float* Wlz  = (const float*)d_in[10]; const float* blz = (const float*)d_in[11];
    const float* Wlr  = (const float*)d_in[12]; const float* blr = (const float*)d_in[13];
    const float* Wlh  = (const float*)d_in[14]; const float* blh = (const float*)d_in[15];
    const float* Whead = (const float*)d_in[16]; const float* bhead = (const float*)d_in[17];

    const int N = in_sizes[0] / F;    // 100000
    const int E = in_sizes[1];        // 1600000
    const int NB = (N + 1023) / 1024;

    float* ws   = (float*)d_ws;
    int*   flag = (int*)ws;                            // [64 pad]
    float* deg  = ws + 64;                             // N
    int*   rowptr = (int*)(deg + N);                   // N+1
    int*   cursor = rowptr + N + 1;                    // N
    int*   cnt    = cursor + N;                        // N
    int*   bsum   = cnt + N;                           // 256
    float* Wc   = (float*)(bsum + 256);                // 3 x 64*128 (fp32 combined)
    float* bc   = Wc + 3 * 64 * 128;                   // 3 x 128
    // 16B-align packed-weight base
    size_t pk_off = (size_t)((bc + 3 * 128) - ws);
    pk_off = (pk_off + 3) & ~(size_t)3;
    short* Wpk  = (short*)(ws + pk_off);               // 3 x 48*512 bf16
    short* Hpk  = Wpk + 3 * 48 * 512;                  // 16*512 bf16
    size_t csr_off = pk_off + (3 * 48 * 512 + 16 * 512) / 2;
    csr_off = (csr_off + 1) & ~(size_t)1;              // 8B align
    int2*  csr  = (int2*)(ws + csr_off);               // E int2

    float* Y  = (float*)d_out;                         // N*64 : holds AX until k_cell
    float* AX = Y;
    float* Hn = Y + (size_t)N * F;                     // N*128

    const long long* ei64 = (const long long*)ei;
    const int*       ei32 = (const int*)ei;

    k_detect<<<1, 256, 0, stream>>>((const unsigned long long*)ei, 1024,
                                    (unsigned long long)N, flag);
    k_init<<<(N + 255) / 256, 256, 0, stream>>>(deg, cnt, N);
    k_hist_deg<<<(E + 255) / 256, 256, 0, stream>>>(ei64, ei32, flag, edge_weight, cnt, deg, E);
    k_scanA<<<NB, 256, 0, stream>>>(cnt, bsum, N);
    k_scanB<<<1, 256, 0, stream>>>(bsum, NB);
    k_scanC<<<NB, 256, 0, stream>>>(cnt, bsum, rowptr, cursor, N, E);
    k_dinv<<<(N + 255) / 256, 256, 0, stream>>>(deg, N);
    k_scatter<<<(E + 255) / 256, 256, 0, stream>>>(ei64, ei32, flag, edge_weight, deg,
                                                   cursor, csr, E);
    k_spmm<<<(N + 3) / 4, 256, 0, stream>>>(csr, rowptr, deg, node_feat, AX, N);

    // combined fp32 weights, then bf16 fragment packs
    k_combine<<<16, 256, 0, stream>>>(Wz, Wlz, bz, blz, Wc,               bc);
    k_combine<<<16, 256, 0, stream>>>(Wr, Wlr, br, blr, Wc + 64 * 128,     bc + 128);
    k_combine<<<16, 256, 0, stream>>>(Wh, Wlh, bh, blh, Wc + 2 * 64 * 128, bc + 256);
    k_pack_gate<<<12, 256, 0, stream>>>(Wc,               Wlz, Wpk);
    k_pack_gate<<<12, 256, 0, stream>>>(Wc + 64 * 128,     Wlr, Wpk + 48 * 512);
    k_pack_gate<<<12, 256, 0, stream>>>(Wc + 2 * 64 * 128, Wlh, Wpk + 2 * 48 * 512);
    k_pack_head<<<4, 256, 0, stream>>>(Whead, Hpk);

    // fused cell: gates + GRU blend + head
    k_cell<<<(N + 63) / 64, 256, 0, stream>>>(AX, H, Wpk, Hpk, bc, bhead, Hn, Y, N);
}

// Round 5
// 491.485 us; speedup vs baseline: 5.2589x; 1.2602x over previous
//
#include <hip/hip_runtime.h>
#include <math.h>

#define F 64
#define HID 128

typedef __attribute__((ext_vector_type(8))) short short8v;
typedef __attribute__((ext_vector_type(4))) float f32x4;
#define MFMA_BF16 __builtin_amdgcn_mfma_f32_16x16x32_bf16

__device__ __forceinline__ unsigned short f2bf(float f) {
    unsigned u = __float_as_uint(f);
    u = (u + 0x7FFFu + ((u >> 16) & 1u)) >> 16;      // round-to-nearest-even
    return (unsigned short)u;
}

__device__ __forceinline__ float fsigmoid(float x) {
    return 1.f / (1.f + __expf(-x));                 // exp(-x)->inf => 0; ->0 => 1
}
__device__ __forceinline__ float ftanh(float x) {
    return 1.f - 2.f / (__expf(2.f * x) + 1.f);      // saturation-safe
}

// ---------------------------------------------------------------------------
// index-width detection: reference declares int64, but the harness/JAX may
// deliver int32. Read first 1024 words as u64: true-int64 values are all < N;
// int32 data packed into u64 is >= 2^32 with overwhelming probability.
__global__ void k_detect(const unsigned long long* p, int n, unsigned long long Nv, int* flag) {
    __shared__ int bad;
    if (threadIdx.x == 0) bad = 0;
    __syncthreads();
    for (int i = threadIdx.x; i < n; i += blockDim.x)
        if (p[i] >= Nv) bad = 1;
    __syncthreads();
    if (threadIdx.x == 0) *flag = bad ? 0 : 1;   // 1 = int64, 0 = int32
}

__device__ __forceinline__ int load_idx(const long long* e64, const int* e32, int f, size_t pos) {
    return f ? (int)e64[pos] : e32[pos];
}

// ---------------------------------------------------------------------------
__global__ void k_init(float* deg, int* cnt, int n) {
    int i = blockIdx.x * 256 + threadIdx.x;
    if (i < n) { deg[i] = 1.0f; cnt[i] = 0; }     // deg starts at self-loop weight
}

__global__ void k_hist_deg(const long long* ei64, const int* ei32, const int* flag,
                           const float* __restrict__ ew, int* cnt, float* deg, int E_) {
    int e = blockIdx.x * 256 + threadIdx.x;
    if (e >= E_) return;
    int f = *flag;
    int d = load_idx(ei64, ei32, f, (size_t)E_ + e);
    atomicAdd(&cnt[d], 1);
    atomicAdd(&deg[d], ew[e]);
}

__global__ void k_dinv(float* deg, int n) {
    int i = blockIdx.x * 256 + threadIdx.x;
    if (i < n) { float v = deg[i]; deg[i] = v > 0.f ? rsqrtf(v) : 0.f; }
}

// ---------------------------------------------------------------------------
// two-level exclusive scan of cnt[n] -> rowptr[n+1] (+ cursor copy)
__global__ void k_scanA(const int* __restrict__ cnt, int* __restrict__ bsum, int n) {
    __shared__ int part[256];
    int tid = threadIdx.x;
    int base = blockIdx.x * 1024 + tid * 4;
    int s = 0;
    #pragma unroll
    for (int t = 0; t < 4; ++t) { int i = base + t; if (i < n) s += cnt[i]; }
    part[tid] = s; __syncthreads();
    for (int off = 128; off > 0; off >>= 1) {
        if (tid < off) part[tid] += part[tid + off];
        __syncthreads();
    }
    if (tid == 0) bsum[blockIdx.x] = part[0];
}

__global__ void k_scanB(int* bsum, int nb) {        // nb <= 256
    __shared__ int sh[256];
    int tid = threadIdx.x;
    int v = (tid < nb) ? bsum[tid] : 0;
    sh[tid] = v; __syncthreads();
    for (int off = 1; off < 256; off <<= 1) {
        int t = (tid >= off) ? sh[tid - off] : 0;
        __syncthreads();
        sh[tid] += t;
        __syncthreads();
    }
    if (tid < nb) bsum[tid] = sh[tid] - v;          // exclusive
}

__global__ void k_scanC(const int* __restrict__ cnt, const int* __restrict__ bsum,
                        int* __restrict__ rowptr, int* __restrict__ cursor, int n, int E_) {
    __shared__ int part[256];
    int tid = threadIdx.x;
    int base = blockIdx.x * 1024;
    int loc[4]; int s = 0;
    #pragma unroll
    for (int t = 0; t < 4; ++t) {
        int i = base + tid * 4 + t;
        int c = (i < n) ? cnt[i] : 0;
        loc[t] = s; s += c;
    }
    part[tid] = s; __syncthreads();
    int mysum = s;
    for (int off = 1; off < 256; off <<= 1) {
        int t = (tid >= off) ? part[tid - off] : 0;
        __syncthreads();
        part[tid] += t;
        __syncthreads();
    }
    int thbase = bsum[blockIdx.x] + part[tid] - mysum;
    #pragma unroll
    for (int t = 0; t < 4; ++t) {
        int i = base + tid * 4 + t;
        if (i < n) { int v = thbase + loc[t]; rowptr[i] = v; cursor[i] = v; }
    }
    if (blockIdx.x == 0 && tid == 0) rowptr[n] = E_;
}

// ---------------------------------------------------------------------------
__global__ void k_scatter(const long long* ei64, const int* ei32, const int* flag,
                          const float* __restrict__ ew, const float* __restrict__ dinv,
                          int* cursor, int2* __restrict__ csr, int E_) {
    int e = blockIdx.x * 256 + threadIdx.x;
    if (e >= E_) return;
    int f = *flag;
    int s = load_idx(ei64, ei32, f, e);
    int d = load_idx(ei64, ei32, f, (size_t)E_ + e);
    float w = dinv[s] * ew[e] * dinv[d];
    int pos = atomicAdd(&cursor[d], 1);
    csr[pos] = make_int2(s, __float_as_int(w));
}

// ---------------------------------------------------------------------------
// AX[i,:] = dinv[i]^2 * X[i,:] + sum_{e in row i} w_e * X[src_e,:]
__launch_bounds__(256)
__global__ void k_spmm(const int2* __restrict__ csr, const int* __restrict__ rowptr,
                       const float* __restrict__ dinv, const float* __restrict__ X,
                       float* __restrict__ AX, int n) {
    int node = blockIdx.x * 4 + (threadIdx.x >> 6);
    int lane = threadIdx.x & 63;
    if (node >= n) return;
    float di = dinv[node];
    float acc = di * di * X[(size_t)node * 64 + lane];
    int beg = rowptr[node], end = rowptr[node + 1];
    for (int j = beg; j < end; ++j) {
        int2 e = csr[j];
        acc = fmaf(__int_as_float(e.y), X[(size_t)e.x * 64 + lane], acc);
    }
    AX[(size_t)node * 64 + lane] = acc;
}

// ---------------------------------------------------------------------------
// Combined gate weights: Wc[64x128] = Wg[64x128] @ Wl_top[128x128],
// bc[128] = blg + bg @ Wl_top.  Grid: 32 blocks x 256 thr (2 rows/block).
__global__ void k_combine(const float* __restrict__ Wg, const float* __restrict__ Wl,
                          const float* __restrict__ bg, const float* __restrict__ blg,
                          float* __restrict__ Wc, float* __restrict__ bc) {
    __shared__ float a[2][128];
    int tid = threadIdx.x;
    int r0 = blockIdx.x * 2;
    { int r = tid >> 7, c = tid & 127; a[r][c] = Wg[(r0 + r) * 128 + c]; }
    __syncthreads();
    int r = tid >> 7, j = tid & 127;
    float s = 0.f;
    for (int k = 0; k < 128; ++k) s = fmaf(a[r][k], Wl[k * 128 + j], s);
    Wc[(r0 + r) * 128 + j] = s;
    if (blockIdx.x == 0 && tid < 128) {
        float s2 = blg[tid];
        for (int k = 0; k < 128; ++k) s2 = fmaf(bg[k], Wl[k * 128 + tid], s2);
        bc[tid] = s2;
    }
}

// ---------------------------------------------------------------------------
// Pack gate B (K=192, Ncol=128) into MFMA-fragment order, bf16.
// frag fi = nt*6+ks; element (lane,j): k = ks*32+(lane>>4)*8+j, col = nt*16+(lane&15)
// source: k<64 -> Wcg[k][col]; k>=64 -> Wl[128+(k-64)][col]
__global__ void k_pack_gate(const float* __restrict__ Wcg, const float* __restrict__ Wl,
                            short* __restrict__ out) {
    int t = blockIdx.x * 256 + threadIdx.x;     // 48*64 threads
    if (t >= 48 * 64) return;
    int fi = t >> 6, lane = t & 63;
    int nt = fi / 6, ks = fi - nt * 6;
    int col = nt * 16 + (lane & 15);
    int kb = ks * 32 + ((lane >> 4) * 8);
    short8v o;
    #pragma unroll
    for (int j = 0; j < 8; ++j) {
        int k = kb + j;
        float v = (k < 64) ? Wcg[k * 128 + col] : Wl[(64 + k) * 128 + col];
        o[j] = (short)f2bf(v);
    }
    *(short8v*)(out + (size_t)fi * 512 + lane * 8) = o;
}

// head B (K=128, Ncol=64): frag fi = nt*4+ks (nt<4, ks<4)
__global__ void k_pack_head(const float* __restrict__ Wh, short* __restrict__ out) {
    int t = blockIdx.x * 256 + threadIdx.x;     // 16*64 threads
    if (t >= 16 * 64) return;
    int fi = t >> 6, lane = t & 63;
    int nt = fi >> 2, ks = fi & 3;
    int col = nt * 16 + (lane & 15);
    int kb = ks * 32 + ((lane >> 4) * 8);
    short8v o;
    #pragma unroll
    for (int j = 0; j < 8; ++j) o[j] = (short)f2bf(Wh[(kb + j) * 64 + col]);
    *(short8v*)(out + (size_t)fi * 512 + lane * 8) = o;
}

// ---------------------------------------------------------------------------
// Fused TGCN cell. 512 threads = 8 waves per 64-row block.
// Wave w: row-group g = w>>1 (16 rows), N-half = w&1 (gates: 4 nt-tiles of 16
// cols; head: 2 nt-tiles). Sequence:
//   stage [AX|H] -> LDS bf16;  Z,R MFMAs;  HR -> LDS;  H-gate MFMAs;
//   Hn = Z*H+(1-Z)*tanh -> global, relu(Hn) -> LDS;  head MFMAs -> Y.
__launch_bounds__(512)
__global__ void k_cell(const float* __restrict__ AXY,    // N x 64 (AX in, Y out)
                       const float* __restrict__ Hm,     // N x 128
                       const short* __restrict__ Wpk,    // 3 x 48 frags x 512
                       const short* __restrict__ Hpk,    // 16 frags x 512
                       const float* __restrict__ bc,     // 3 x 128
                       const float* __restrict__ bhead,  // 64
                       float* __restrict__ Hn,           // N x 128 out
                       float* __restrict__ Yout,         // N x 64 out (== AXY)
                       int n) {
    __shared__ short As[64 * 200];    // [row][k 0..191], 400B stride (25x16B, odd)
    __shared__ short HRs[64 * 136];   // [row][k2 0..127], 272B stride (17x16B, odd)
    int tid = threadIdx.x;
    int w = tid >> 6, lane = tid & 63;
    int g = w >> 1, half = w & 1;
    int row0 = blockIdx.x * 64;

    // ---- cooperative stage: 64 rows of [AX | H] as bf16 ----
    const float4* AX4 = (const float4*)AXY;
    const float4* H4  = (const float4*)Hm;
    #pragma unroll
    for (int it = 0; it < 6; ++it) {
        int q = it * 512 + tid;              // 64*48 = 3072 float4s
        int r = q / 48, c4 = q - r * 48;
        int grow = row0 + r;
        float4 v = make_float4(0.f, 0.f, 0.f, 0.f);
        if (grow < n) v = (c4 < 16) ? AX4[(size_t)grow * 16 + c4]
                                    : H4[(size_t)grow * 32 + (c4 - 16)];
        short4 s4;
        s4.x = (short)f2bf(v.x); s4.y = (short)f2bf(v.y);
        s4.z = (short)f2bf(v.z); s4.w = (short)f2bf(v.w);
        *(short4*)&As[r * 200 + c4 * 4] = s4;
    }
    __syncthreads();

    int arow = g * 16 + (lane & 15);
    int kg = (lane >> 4) * 8;

    short8v afr[6];
    #pragma unroll
    for (int ks = 0; ks < 6; ++ks)
        afr[ks] = *(const short8v*)&As[arow * 200 + ks * 32 + kg];

    const short8v* Bz = (const short8v*)Wpk;
    const short8v* Br = (const short8v*)(Wpk + 48 * 512);
    const short8v* Bh = (const short8v*)(Wpk + 2 * 48 * 512);

    // ---- z & r gates: 4 nt-tiles per wave ----
    f32x4 accz[4] = {};
    f32x4 accr[4] = {};
    #pragma unroll
    for (int j = 0; j < 4; ++j) {
        int nt = half * 4 + j;
        #pragma unroll
        for (int ks = 0; ks < 6; ++ks)
            accz[j] = MFMA_BF16(afr[ks], Bz[(nt * 6 + ks) * 64 + lane], accz[j], 0, 0, 0);
        #pragma unroll
        for (int ks = 0; ks < 6; ++ks)
            accr[j] = MFMA_BF16(afr[ks], Br[(nt * 6 + ks) * 64 + lane], accr[j], 0, 0, 0);
    }

    // ---- z/r epilogue: Z stays in accz regs, HR -> LDS bf16 ----
    #pragma unroll
    for (int j = 0; j < 4; ++j) {
        int col = (half * 4 + j) * 16 + (lane & 15);
        float bzv = bc[col];
        float brv = bc[128 + col];
        #pragma unroll
        for (int i = 0; i < 4; ++i) {
            int lrow = g * 16 + (lane >> 4) * 4 + i;
            int grow = row0 + lrow;
            float z = fsigmoid(accz[j][i] + bzv);
            float hv = (grow < n) ? Hm[(size_t)grow * 128 + col] : 0.f;
            float hr = hv * fsigmoid(accr[j][i] + brv);
            accz[j][i] = z;
            HRs[lrow * 136 + col] = (short)f2bf(hr);
        }
    }
    __syncthreads();                       // HR complete (both halves)

    // ---- h gate: A = [AX | HR] ----
    short8v ahr[6];
    ahr[0] = afr[0]; ahr[1] = afr[1];
    #pragma unroll
    for (int ks = 0; ks < 4; ++ks)
        ahr[2 + ks] = *(const short8v*)&HRs[arow * 136 + ks * 32 + kg];
    f32x4 acch[4] = {};
    #pragma unroll
    for (int j = 0; j < 4; ++j) {
        int nt = half * 4 + j;
        #pragma unroll
        for (int ks = 0; ks < 6; ++ks)
            acch[j] = MFMA_BF16(ahr[ks], Bh[(nt * 6 + ks) * 64 + lane], acch[j], 0, 0, 0);
    }
    __syncthreads();                       // all HR reads done before relu overwrite

    // ---- h epilogue: Hn -> global, relu(Hn) -> LDS (reuse HRs) ----
    #pragma unroll
    for (int j = 0; j < 4; ++j) {
        int col = (half * 4 + j) * 16 + (lane & 15);
        float bhv = bc[256 + col];
        #pragma unroll
        for (int i = 0; i < 4; ++i) {
            int lrow = g * 16 + (lane >> 4) * 4 + i;
            int grow = row0 + lrow;
            float th = ftanh(acch[j][i] + bhv);
            float z = accz[j][i];
            float hv = (grow < n) ? Hm[(size_t)grow * 128 + col] : 0.f;
            float hn = z * hv + (1.f - z) * th;
            if (grow < n) Hn[(size_t)grow * 128 + col] = hn;
            HRs[lrow * 136 + col] = (short)f2bf(fmaxf(hn, 0.f));
        }
    }
    __syncthreads();                       // relu(Hn) complete

    // ---- head: Y = relu(Hn) @ Bhead + bhead (2 nt-tiles per wave) ----
    short8v ay[4];
    #pragma unroll
    for (int ks = 0; ks < 4; ++ks)
        ay[ks] = *(const short8v*)&HRs[arow * 136 + ks * 32 + kg];
    const short8v* By = (const short8v*)Hpk;
    f32x4 accy[2] = {};
    #pragma unroll
    for (int j = 0; j < 2; ++j) {
        int nt = half * 2 + j;
        #pragma unroll
        for (int ks = 0; ks < 4; ++ks)
            accy[j] = MFMA_BF16(ay[ks], By[(nt * 4 + ks) * 64 + lane], accy[j], 0, 0, 0);
    }
    #pragma unroll
    for (int j = 0; j < 2; ++j) {
        int col = (half * 2 + j) * 16 + (lane & 15);
        float by = bhead[col];
        #pragma unroll
        for (int i = 0; i < 4; ++i) {
            int grow = row0 + g * 16 + (lane >> 4) * 4 + i;
            if (grow < n) Yout[(size_t)grow * 64 + col] = accy[j][i] + by;
        }
    }
}

// ---------------------------------------------------------------------------
extern "C" void kernel_launch(void* const* d_in, const int* in_sizes, int n_in,
                              void* d_out, int out_size, void* d_ws, size_t ws_size,
                              hipStream_t stream) {
    const float* node_feat   = (const float*)d_in[0];
    const float* edge_weight = (const float*)d_in[1];
    const float* H           = (const float*)d_in[2];
    const void*  ei          = d_in[3];
    const float* Wz   = (const float*)d_in[4];  const float* bz = (const float*)d_in[5];
    const float* Wr   = (const float*)d_in[6];  const float* br = (const float*)d_in[7];
    const float* Wh   = (const float*)d_in[8];  const float* bh = (const float*)d_in[9];
    const float* Wlz  = (const float*)d_in[10]; const float* blz = (const float*)d_in[11];
    const float* Wlr  = (const float*)d_in[12]; const float* blr = (const float*)d_in[13];
    const float* Wlh  = (const float*)d_in[14]; const float* blh = (const float*)d_in[15];
    const float* Whead = (const float*)d_in[16]; const float* bhead = (const float*)d_in[17];

    const int N = in_sizes[0] / F;    // 100000
    const int E = in_sizes[1];        // 1600000
    const int NB = (N + 1023) / 1024;

    float* ws   = (float*)d_ws;
    int*   flag = (int*)ws;                            // [64 pad]
    float* deg  = ws + 64;                             // N
    int*   rowptr = (int*)(deg + N);                   // N+1
    int*   cursor = rowptr + N + 1;                    // N
    int*   cnt    = cursor + N;                        // N
    int*   bsum   = cnt + N;                           // 256
    float* Wc   = (float*)(bsum + 256);                // 3 x 64*128 (fp32 combined)
    float* bc   = Wc + 3 * 64 * 128;                   // 3 x 128
    // 16B-align packed-weight base
    size_t pk_off = (size_t)((bc + 3 * 128) - ws);
    pk_off = (pk_off + 3) & ~(size_t)3;
    short* Wpk  = (short*)(ws + pk_off);               // 3 x 48*512 bf16
    short* Hpk  = Wpk + 3 * 48 * 512;                  // 16*512 bf16
    size_t csr_off = pk_off + (3 * 48 * 512 + 16 * 512) / 2;
    csr_off = (csr_off + 1) & ~(size_t)1;              // 8B align
    int2*  csr  = (int2*)(ws + csr_off);               // E int2

    float* Y  = (float*)d_out;                         // N*64 : holds AX until k_cell
    float* AX = Y;
    float* Hn = Y + (size_t)N * F;                     // N*128

    const long long* ei64 = (const long long*)ei;
    const int*       ei32 = (const int*)ei;

    k_detect<<<1, 256, 0, stream>>>((const unsigned long long*)ei, 1024,
                                    (unsigned long long)N, flag);
    k_init<<<(N + 255) / 256, 256, 0, stream>>>(deg, cnt, N);
    k_hist_deg<<<(E + 255) / 256, 256, 0, stream>>>(ei64, ei32, flag, edge_weight, cnt, deg, E);
    k_scanA<<<NB, 256, 0, stream>>>(cnt, bsum, N);
    k_scanB<<<1, 256, 0, stream>>>(bsum, NB);
    k_scanC<<<NB, 256, 0, stream>>>(cnt, bsum, rowptr, cursor, N, E);
    k_dinv<<<(N + 255) / 256, 256, 0, stream>>>(deg, N);
    k_scatter<<<(E + 255) / 256, 256, 0, stream>>>(ei64, ei32, flag, edge_weight, deg,
                                                   cursor, csr, E);
    k_spmm<<<(N + 3) / 4, 256, 0, stream>>>(csr, rowptr, deg, node_feat, AX, N);

    // combined fp32 weights (32 blocks each), then bf16 fragment packs
    k_combine<<<32, 256, 0, stream>>>(Wz, Wlz, bz, blz, Wc,               bc);
    k_combine<<<32, 256, 0, stream>>>(Wr, Wlr, br, blr, Wc + 64 * 128,     bc + 128);
    k_combine<<<32, 256, 0, stream>>>(Wh, Wlh, bh, blh, Wc + 2 * 64 * 128, bc + 256);
    k_pack_gate<<<12, 256, 0, stream>>>(Wc,               Wlz, Wpk);
    k_pack_gate<<<12, 256, 0, stream>>>(Wc + 64 * 128,     Wlr, Wpk + 48 * 512);
    k_pack_gate<<<12, 256, 0, stream>>>(Wc + 2 * 64 * 128, Wlh, Wpk + 2 * 48 * 512);
    k_pack_head<<<4, 256, 0, stream>>>(Whead, Hpk);

    // fused cell: gates + GRU blend + head (512 threads / 64 rows)
    k_cell<<<(N + 63) / 64, 512, 0, stream>>>(AX, H, Wpk, Hpk, bc, bhead, Hn, Y, N);
}

// Round 6
// 488.192 us; speedup vs baseline: 5.2944x; 1.0067x over previous
//
#include <hip/hip_runtime.h>
#include <math.h>

#define F 64
#define HID 128

typedef __attribute__((ext_vector_type(8))) short short8v;
typedef __attribute__((ext_vector_type(4))) float f32x4;
#define MFMA_BF16 __builtin_amdgcn_mfma_f32_16x16x32_bf16

__device__ __forceinline__ unsigned short f2bf(float f) {
    unsigned u = __float_as_uint(f);
    u = (u + 0x7FFFu + ((u >> 16) & 1u)) >> 16;      // round-to-nearest-even
    return (unsigned short)u;
}
__device__ __forceinline__ float bf2f(unsigned short b) {
    return __uint_as_float((unsigned)b << 16);
}
__device__ __forceinline__ float fsigmoid(float x) {
    return 1.f / (1.f + __expf(-x));
}
__device__ __forceinline__ float ftanh(float x) {
    return 1.f - 2.f / (__expf(2.f * x) + 1.f);      // saturation-safe
}

// ---------------------------------------------------------------------------
// index-width detection (int64 per reference vs int32 if JAX x64 off)
__global__ void k_detect(const unsigned long long* p, int n, unsigned long long Nv, int* flag) {
    __shared__ int bad;
    if (threadIdx.x == 0) bad = 0;
    __syncthreads();
    for (int i = threadIdx.x; i < n; i += blockDim.x)
        if (p[i] >= Nv) bad = 1;
    __syncthreads();
    if (threadIdx.x == 0) *flag = bad ? 0 : 1;   // 1 = int64, 0 = int32
}

__device__ __forceinline__ int load_idx(const long long* e64, const int* e32, int f, size_t pos) {
    return f ? (int)e64[pos] : e32[pos];
}

// ---------------------------------------------------------------------------
// X -> bf16 table + deg/cnt init.  grid covers n*16 float4s.
__global__ void k_prep(const float* __restrict__ X, unsigned short* __restrict__ Xb,
                       float* deg, int* cnt, int n) {
    int t = blockIdx.x * 256 + threadIdx.x;
    if (t < n * 16) {
        float4 v = ((const float4*)X)[t];
        ushort4 o;
        o.x = f2bf(v.x); o.y = f2bf(v.y); o.z = f2bf(v.z); o.w = f2bf(v.w);
        ((ushort4*)Xb)[t] = o;
    }
    if (t < n) { deg[t] = 1.0f; cnt[t] = 0; }
}

__global__ void k_hist_deg(const long long* ei64, const int* ei32, const int* flag,
                           const float* __restrict__ ew, int* cnt, float* deg, int E_) {
    int e = blockIdx.x * 256 + threadIdx.x;
    if (e >= E_) return;
    int f = *flag;
    int d = load_idx(ei64, ei32, f, (size_t)E_ + e);
    atomicAdd(&cnt[d], 1);
    atomicAdd(&deg[d], ew[e]);
}

// ---------------------------------------------------------------------------
// two-level exclusive scan of cnt[n] -> rowptr[n+1] (+ cursor copy), + dinv
__global__ void k_scanA(const int* __restrict__ cnt, int* __restrict__ bsum, int n) {
    __shared__ int part[256];
    int tid = threadIdx.x;
    int base = blockIdx.x * 1024 + tid * 4;
    int s = 0;
    #pragma unroll
    for (int t = 0; t < 4; ++t) { int i = base + t; if (i < n) s += cnt[i]; }
    part[tid] = s; __syncthreads();
    for (int off = 128; off > 0; off >>= 1) {
        if (tid < off) part[tid] += part[tid + off];
        __syncthreads();
    }
    if (tid == 0) bsum[blockIdx.x] = part[0];
}

__global__ void k_scanB(int* bsum, int nb) {        // nb <= 256
    __shared__ int sh[256];
    int tid = threadIdx.x;
    int v = (tid < nb) ? bsum[tid] : 0;
    sh[tid] = v; __syncthreads();
    for (int off = 1; off < 256; off <<= 1) {
        int t = (tid >= off) ? sh[tid - off] : 0;
        __syncthreads();
        sh[tid] += t;
        __syncthreads();
    }
    if (tid < nb) bsum[tid] = sh[tid] - v;          // exclusive
}

__global__ void k_scanC(const int* __restrict__ cnt, const int* __restrict__ bsum,
                        int* __restrict__ rowptr, int* __restrict__ cursor,
                        float* __restrict__ deg, int n, int E_) {
    __shared__ int part[256];
    int tid = threadIdx.x;
    int base = blockIdx.x * 1024;
    int loc[4]; int s = 0;
    #pragma unroll
    for (int t = 0; t < 4; ++t) {
        int i = base + tid * 4 + t;
        int c = (i < n) ? cnt[i] : 0;
        loc[t] = s; s += c;
    }
    part[tid] = s; __syncthreads();
    int mysum = s;
    for (int off = 1; off < 256; off <<= 1) {
        int t = (tid >= off) ? part[tid - off] : 0;
        __syncthreads();
        part[tid] += t;
        __syncthreads();
    }
    int thbase = bsum[blockIdx.x] + part[tid] - mysum;
    #pragma unroll
    for (int t = 0; t < 4; ++t) {
        int i = base + tid * 4 + t;
        if (i < n) {
            int v = thbase + loc[t]; rowptr[i] = v; cursor[i] = v;
            float dv = deg[i]; deg[i] = dv > 0.f ? rsqrtf(dv) : 0.f;   // dinv fold
        }
    }
    if (blockIdx.x == 0 && tid == 0) rowptr[n] = E_;
}

// ---------------------------------------------------------------------------
__global__ void k_scatter(const long long* ei64, const int* ei32, const int* flag,
                          const float* __restrict__ ew, const float* __restrict__ dinv,
                          int* cursor, int2* __restrict__ csr, int E_) {
    int e = blockIdx.x * 256 + threadIdx.x;
    if (e >= E_) return;
    int f = *flag;
    int s = load_idx(ei64, ei32, f, e);
    int d = load_idx(ei64, ei32, f, (size_t)E_ + e);
    float w = dinv[s] * ew[e] * dinv[d];
    int pos = atomicAdd(&cursor[d], 1);
    csr[pos] = make_int2(s, __float_as_int(w));
}

// ---------------------------------------------------------------------------
// AXb[i,:] = bf16( dinv[i]^2 * Xb[i,:] + sum_e w_e * Xb[src_e,:] )
__launch_bounds__(256)
__global__ void k_spmm(const int2* __restrict__ csr, const int* __restrict__ rowptr,
                       const float* __restrict__ dinv, const unsigned short* __restrict__ Xb,
                       unsigned short* __restrict__ AXb, int n) {
    int node = blockIdx.x * 4 + (threadIdx.x >> 6);
    int lane = threadIdx.x & 63;
    if (node >= n) return;
    float di = dinv[node];
    float acc = di * di * bf2f(Xb[(size_t)node * 64 + lane]);
    int j = rowptr[node], end = rowptr[node + 1];
    for (; j + 1 < end; j += 2) {
        int2 e0 = csr[j];
        int2 e1 = csr[j + 1];
        float x0 = bf2f(Xb[(size_t)e0.x * 64 + lane]);
        float x1 = bf2f(Xb[(size_t)e1.x * 64 + lane]);
        acc = fmaf(__int_as_float(e0.y), x0, acc);
        acc = fmaf(__int_as_float(e1.y), x1, acc);
    }
    if (j < end) {
        int2 e = csr[j];
        acc = fmaf(__int_as_float(e.y), bf2f(Xb[(size_t)e.x * 64 + lane]), acc);
    }
    AXb[(size_t)node * 64 + lane] = f2bf(acc);
}

// ---------------------------------------------------------------------------
// Weight prep, one block per gate (0..2) + head pack (block 3).
// gate: Wc = Wg @ Wl_top (LDS), bc = blg + bg @ Wl_top; pack 48 frags bf16.
// frag fi = nt*6+ks; (lane,j): k = ks*32+(lane>>4)*8+j, col = nt*16+(lane&15)
__launch_bounds__(512)
__global__ void k_wprep(const float* __restrict__ Wz, const float* __restrict__ Wr,
                        const float* __restrict__ Wh,
                        const float* __restrict__ Wlz, const float* __restrict__ Wlr,
                        const float* __restrict__ Wlh,
                        const float* __restrict__ bz, const float* __restrict__ br,
                        const float* __restrict__ bh,
                        const float* __restrict__ blz, const float* __restrict__ blr,
                        const float* __restrict__ blh,
                        const float* __restrict__ Whead,
                        short* __restrict__ Wpk, short* __restrict__ Hpk,
                        float* __restrict__ bc) {
    int tid = threadIdx.x;
    int gate = blockIdx.x;
    if (gate == 3) {   // head pack: K=128, 64 cols, 16 frags
        #pragma unroll
        for (int it = 0; it < 2; ++it) {
            int idx = it * 512 + tid;              // < 1024
            int fi = idx >> 6, lane = idx & 63;
            int nt = fi >> 2, ks = fi & 3;
            int col = nt * 16 + (lane & 15);
            int kb = ks * 32 + ((lane >> 4) * 8);
            short8v o;
            #pragma unroll
            for (int j = 0; j < 8; ++j) o[j] = (short)f2bf(Whead[(kb + j) * 64 + col]);
            *(short8v*)(Hpk + (size_t)fi * 512 + lane * 8) = o;
        }
        return;
    }
    const float* Wg  = gate == 0 ? Wz  : gate == 1 ? Wr  : Wh;
    const float* Wl  = gate == 0 ? Wlz : gate == 1 ? Wlr : Wlh;
    const float* bg  = gate == 0 ? bz  : gate == 1 ? br  : bh;
    const float* blg = gate == 0 ? blz : gate == 1 ? blr : blh;
    __shared__ float wc[64 * 128];
    for (int o = tid; o < 64 * 128; o += 512) {
        int r = o >> 7, j = o & 127;
        float s = 0.f;
        for (int k = 0; k < 128; ++k) s = fmaf(Wg[r * 128 + k], Wl[k * 128 + j], s);
        wc[o] = s;
    }
    if (tid < 128) {
        float s = blg[tid];
        for (int k = 0; k < 128; ++k) s = fmaf(bg[k], Wl[k * 128 + tid], s);
        bc[gate * 128 + tid] = s;
    }
    __syncthreads();
    short* out = Wpk + (size_t)gate * 48 * 512;
    #pragma unroll
    for (int it = 0; it < 6; ++it) {
        int idx = it * 512 + tid;                  // < 3072
        int fi = idx >> 6, lane = idx & 63;
        int nt = fi / 6, ks = fi - nt * 6;
        int col = nt * 16 + (lane & 15);
        int kb = ks * 32 + ((lane >> 4) * 8);
        short8v o;
        #pragma unroll
        for (int j = 0; j < 8; ++j) {
            int k = kb + j;
            float v = (k < 64) ? wc[k * 128 + col] : Wl[(64 + k) * 128 + col];
            o[j] = (short)f2bf(v);
        }
        *(short8v*)(out + (size_t)fi * 512 + lane * 8) = o;
    }
}

// ---------------------------------------------------------------------------
// Fused TGCN cell. 512 threads = 8 waves / 64-row block. Wave w: rows g=w>>1,
// N-half = w&1. A-fragments loaded per-lane directly from global (AXb bf16,
// H fp32->bf16); only HR/relu round-trips through LDS.
__launch_bounds__(512)
__global__ void k_cell(const unsigned short* __restrict__ AXb,   // N x 64 bf16
                       const float* __restrict__ Hm,             // N x 128
                       const short* __restrict__ Wpk,            // 3 x 48 x 512
                       const short* __restrict__ Hpk,            // 16 x 512
                       const float* __restrict__ bc,             // 3 x 128
                       const float* __restrict__ bhead,          // 64
                       float* __restrict__ Hn,                   // N x 128 out
                       float* __restrict__ Yout,                 // N x 64 out
                       int n) {
    __shared__ short HRs[64 * 136];   // [row][k2 0..127], 272B stride
    int tid = threadIdx.x;
    int w = tid >> 6, lane = tid & 63;
    int g = w >> 1, half = w & 1;
    int row0 = blockIdx.x * 64;

    int arow = g * 16 + (lane & 15);           // local row of this lane's A-frags
    int cr = row0 + arow; if (cr > n - 1) cr = n - 1;
    int kg = (lane >> 4) * 8;

    // ---- A-fragments: AX (2 frags, bf16 direct) + H (4 frags, converted) ----
    short8v afr0 = *(const short8v*)&AXb[(size_t)cr * 64 + kg];
    short8v afr1 = *(const short8v*)&AXb[(size_t)cr * 64 + 32 + kg];
    short8v ah[4];
    #pragma unroll
    for (int ks = 0; ks < 4; ++ks) {
        const float* hp = &Hm[(size_t)cr * 128 + ks * 32 + kg];
        float4 a = *(const float4*)hp;
        float4 b = *(const float4*)(hp + 4);
        short8v o;
        o[0] = (short)f2bf(a.x); o[1] = (short)f2bf(a.y);
        o[2] = (short)f2bf(a.z); o[3] = (short)f2bf(a.w);
        o[4] = (short)f2bf(b.x); o[5] = (short)f2bf(b.y);
        o[6] = (short)f2bf(b.z); o[7] = (short)f2bf(b.w);
        ah[ks] = o;
    }

    const short8v* Bz = (const short8v*)Wpk;
    const short8v* Br = (const short8v*)(Wpk + 48 * 512);
    const short8v* Bh = (const short8v*)(Wpk + 2 * 48 * 512);

    // ---- z & r gates: 4 nt-tiles per wave ----
    f32x4 accz[4] = {};
    f32x4 accr[4] = {};
    #pragma unroll
    for (int j = 0; j < 4; ++j) {
        int nt = half * 4 + j;
        accz[j] = MFMA_BF16(afr0,  Bz[(nt * 6 + 0) * 64 + lane], accz[j], 0, 0, 0);
        accz[j] = MFMA_BF16(afr1,  Bz[(nt * 6 + 1) * 64 + lane], accz[j], 0, 0, 0);
        #pragma unroll
        for (int ks = 0; ks < 4; ++ks)
            accz[j] = MFMA_BF16(ah[ks], Bz[(nt * 6 + 2 + ks) * 64 + lane], accz[j], 0, 0, 0);
        accr[j] = MFMA_BF16(afr0,  Br[(nt * 6 + 0) * 64 + lane], accr[j], 0, 0, 0);
        accr[j] = MFMA_BF16(afr1,  Br[(nt * 6 + 1) * 64 + lane], accr[j], 0, 0, 0);
        #pragma unroll
        for (int ks = 0; ks < 4; ++ks)
            accr[j] = MFMA_BF16(ah[ks], Br[(nt * 6 + 2 + ks) * 64 + lane], accr[j], 0, 0, 0);
    }

    // ---- z/r epilogue: Z stays in accz regs, HR -> LDS bf16 ----
    #pragma unroll
    for (int j = 0; j < 4; ++j) {
        int col = (half * 4 + j) * 16 + (lane & 15);
        float bzv = bc[col];
        float brv = bc[128 + col];
        #pragma unroll
        for (int i = 0; i < 4; ++i) {
            int lrow = g * 16 + (lane >> 4) * 4 + i;
            int grow = row0 + lrow;
            float z = fsigmoid(accz[j][i] + bzv);
            float hv = (grow < n) ? Hm[(size_t)grow * 128 + col] : 0.f;
            float hr = hv * fsigmoid(accr[j][i] + brv);
            accz[j][i] = z;
            HRs[lrow * 136 + col] = (short)f2bf(hr);
        }
    }
    __syncthreads();                       // HR complete (both halves)

    // ---- h gate: A = [AX | HR] ----
    short8v ahr[4];
    #pragma unroll
    for (int ks = 0; ks < 4; ++ks)
        ahr[ks] = *(const short8v*)&HRs[arow * 136 + ks * 32 + kg];
    f32x4 acch[4] = {};
    #pragma unroll
    for (int j = 0; j < 4; ++j) {
        int nt = half * 4 + j;
        acch[j] = MFMA_BF16(afr0,   Bh[(nt * 6 + 0) * 64 + lane], acch[j], 0, 0, 0);
        acch[j] = MFMA_BF16(afr1,   Bh[(nt * 6 + 1) * 64 + lane], acch[j], 0, 0, 0);
        #pragma unroll
        for (int ks = 0; ks < 4; ++ks)
            acch[j] = MFMA_BF16(ahr[ks], Bh[(nt * 6 + 2 + ks) * 64 + lane], acch[j], 0, 0, 0);
    }
    __syncthreads();                       // all HR reads done before overwrite

    // ---- h epilogue: Hn -> global, relu(Hn) -> LDS (reuse HRs) ----
    #pragma unroll
    for (int j = 0; j < 4; ++j) {
        int col = (half * 4 + j) * 16 + (lane & 15);
        float bhv = bc[256 + col];
        #pragma unroll
        for (int i = 0; i < 4; ++i) {
            int lrow = g * 16 + (lane >> 4) * 4 + i;
            int grow = row0 + lrow;
            float th = ftanh(acch[j][i] + bhv);
            float z = accz[j][i];
            float hv = (grow < n) ? Hm[(size_t)grow * 128 + col] : 0.f;
            float hn = z * hv + (1.f - z) * th;
            if (grow < n) Hn[(size_t)grow * 128 + col] = hn;
            HRs[lrow * 136 + col] = (short)f2bf(fmaxf(hn, 0.f));
        }
    }
    __syncthreads();                       // relu(Hn) complete

    // ---- head: Y = relu(Hn) @ Bhead + bhead (2 nt-tiles per wave) ----
    short8v ay[4];
    #pragma unroll
    for (int ks = 0; ks < 4; ++ks)
        ay[ks] = *(const short8v*)&HRs[arow * 136 + ks * 32 + kg];
    const short8v* By = (const short8v*)Hpk;
    f32x4 accy[2] = {};
    #pragma unroll
    for (int j = 0; j < 2; ++j) {
        int nt = half * 2 + j;
        #pragma unroll
        for (int ks = 0; ks < 4; ++ks)
            accy[j] = MFMA_BF16(ay[ks], By[(nt * 4 + ks) * 64 + lane], accy[j], 0, 0, 0);
    }
    #pragma unroll
    for (int j = 0; j < 2; ++j) {
        int col = (half * 2 + j) * 16 + (lane & 15);
        float by = bhead[col];
        #pragma unroll
        for (int i = 0; i < 4; ++i) {
            int grow = row0 + g * 16 + (lane >> 4) * 4 + i;
            if (grow < n) Yout[(size_t)grow * 64 + col] = accy[j][i] + by;
        }
    }
}

// ---------------------------------------------------------------------------
extern "C" void kernel_launch(void* const* d_in, const int* in_sizes, int n_in,
                              void* d_out, int out_size, void* d_ws, size_t ws_size,
                              hipStream_t stream) {
    const float* node_feat   = (const float*)d_in[0];
    const float* edge_weight = (const float*)d_in[1];
    const float* H           = (const float*)d_in[2];
    const void*  ei          = d_in[3];
    const float* Wz   = (const float*)d_in[4];  const float* bz = (const float*)d_in[5];
    const float* Wr   = (const float*)d_in[6];  const float* br = (const float*)d_in[7];
    const float* Wh   = (const float*)d_in[8];  const float* bh = (const float*)d_in[9];
    const float* Wlz  = (const float*)d_in[10]; const float* blz = (const float*)d_in[11];
    const float* Wlr  = (const float*)d_in[12]; const float* blr = (const float*)d_in[13];
    const float* Wlh  = (const float*)d_in[14]; const float* blh = (const float*)d_in[15];
    const float* Whead = (const float*)d_in[16]; const float* bhead = (const float*)d_in[17];

    const int N = in_sizes[0] / F;    // 100000
    const int E = in_sizes[1];        // 1600000
    const int NB = (N + 1023) / 1024;

    float* ws   = (float*)d_ws;
    int*   flag = (int*)ws;                            // [64 pad]
    float* deg  = ws + 64;                             // N (becomes dinv in scanC)
    int*   rowptr = (int*)(deg + N);                   // N+1
    int*   cursor = rowptr + N + 1;                    // N
    int*   cnt    = cursor + N;                        // N
    int*   bsum   = cnt + N;                           // 256
    float* bc   = (float*)(bsum + 256);                // 3 x 128
    size_t pk_off = (size_t)((bc + 3 * 128) - ws);
    pk_off = (pk_off + 3) & ~(size_t)3;                // 16B align
    short* Wpk  = (short*)(ws + pk_off);               // 3 x 48*512 bf16
    short* Hpk  = Wpk + 3 * 48 * 512;                  // 16*512 bf16
    size_t xb_off = pk_off + (3 * 48 * 512 + 16 * 512) / 2;
    xb_off = (xb_off + 1) & ~(size_t)1;                // 8B align
    unsigned short* Xb  = (unsigned short*)(ws + xb_off);   // N*64 bf16
    unsigned short* AXb = Xb + (size_t)N * 64;              // N*64 bf16
    size_t csr_off = xb_off + (size_t)N * 64;          // (2 x N*64 shorts = N*64 floats)
    csr_off = (csr_off + 1) & ~(size_t)1;
    int2*  csr  = (int2*)(ws + csr_off);               // E int2

    float* Y  = (float*)d_out;                         // N*64
    float* Hn = Y + (size_t)N * F;                     // N*128

    const long long* ei64 = (const long long*)ei;
    const int*       ei32 = (const int*)ei;

    k_detect<<<1, 256, 0, stream>>>((const unsigned long long*)ei, 1024,
                                    (unsigned long long)N, flag);
    k_prep<<<(N * 16 + 255) / 256, 256, 0, stream>>>(node_feat, Xb, deg, cnt, N);
    k_hist_deg<<<(E + 255) / 256, 256, 0, stream>>>(ei64, ei32, flag, edge_weight, cnt, deg, E);
    k_scanA<<<NB, 256, 0, stream>>>(cnt, bsum, N);
    k_scanB<<<1, 256, 0, stream>>>(bsum, NB);
    k_scanC<<<NB, 256, 0, stream>>>(cnt, bsum, rowptr, cursor, deg, N, E);
    k_scatter<<<(E + 255) / 256, 256, 0, stream>>>(ei64, ei32, flag, edge_weight, deg,
                                                   cursor, csr, E);
    k_spmm<<<(N + 3) / 4, 256, 0, stream>>>(csr, rowptr, deg, Xb, AXb, N);

    k_wprep<<<4, 512, 0, stream>>>(Wz, Wr, Wh, Wlz, Wlr, Wlh,
                                   bz, br, bh, blz, blr, blh, Whead, Wpk, Hpk, bc);

    k_cell<<<(N + 63) / 64, 512, 0, stream>>>(AXb, H, Wpk, Hpk, bc, bhead, Hn, Y, N);
}

// Round 7
// 381.650 us; speedup vs baseline: 6.7724x; 1.2792x over previous
//
#include <hip/hip_runtime.h>
#include <math.h>

#define F 64
#define HID 128

typedef __attribute__((ext_vector_type(8))) short short8v;
typedef __attribute__((ext_vector_type(4))) float f32x4;
#define MFMA_BF16 __builtin_amdgcn_mfma_f32_16x16x32_bf16

#define CNT_SHIFT 52
#define W_MASK ((1ULL << 52) - 1)
#define W_SCALE 549755813888.0f            // 2^39
#define W_INV 1.8189894035458565e-12       // 2^-39

__device__ __forceinline__ unsigned short f2bf(float f) {
    unsigned u = __float_as_uint(f);
    u = (u + 0x7FFFu + ((u >> 16) & 1u)) >> 16;      // round-to-nearest-even
    return (unsigned short)u;
}
__device__ __forceinline__ float bf2f(unsigned short b) {
    return __uint_as_float((unsigned)b << 16);
}
__device__ __forceinline__ float fsigmoid(float x) {
    return 1.f / (1.f + __expf(-x));
}
__device__ __forceinline__ float ftanh(float x) {
    return 1.f - 2.f / (__expf(2.f * x) + 1.f);      // saturation-safe
}

// ---------------------------------------------------------------------------
// index-width detection (int64 per reference vs int32 if JAX x64 off)
__global__ void k_detect(const unsigned long long* p, int n, unsigned long long Nv, int* flag) {
    __shared__ int bad;
    if (threadIdx.x == 0) bad = 0;
    __syncthreads();
    for (int i = threadIdx.x; i < n; i += blockDim.x)
        if (p[i] >= Nv) bad = 1;
    __syncthreads();
    if (threadIdx.x == 0) *flag = bad ? 0 : 1;   // 1 = int64, 0 = int32
}

__device__ __forceinline__ int load_idx(const long long* e64, const int* e32, int f, size_t pos) {
    return f ? (int)e64[pos] : e32[pos];
}

// ---------------------------------------------------------------------------
// X -> bf16 table + packed (cnt|deg) zero-init.  grid covers n*16 float4s.
__global__ void k_prep(const float* __restrict__ X, unsigned short* __restrict__ Xb,
                       unsigned long long* pcnt, int n) {
    int t = blockIdx.x * 256 + threadIdx.x;
    if (t < n * 16) {
        float4 v = ((const float4*)X)[t];
        ushort4 o;
        o.x = f2bf(v.x); o.y = f2bf(v.y); o.z = f2bf(v.z); o.w = f2bf(v.w);
        ((ushort4*)Xb)[t] = o;
    }
    if (t < n) pcnt[t] = 0ULL;
}

// one packed u64 atomic per edge: count in high bits, fixed-point weight low.
// Returned old value's count field = this edge's rank within its dst row.
__global__ void k_hist(const long long* ei64, const int* ei32, const int* flag,
                       const float* __restrict__ ew, unsigned long long* pcnt,
                       unsigned short* __restrict__ rank, int E_) {
    int e = blockIdx.x * 256 + threadIdx.x;
    if (e >= E_) return;
    int f = *flag;
    int d = load_idx(ei64, ei32, f, (size_t)E_ + e);
    unsigned long long enc = (1ULL << CNT_SHIFT) |
                             (unsigned long long)(ew[e] * W_SCALE);
    unsigned long long old = atomicAdd(&pcnt[d], enc);
    rank[e] = (unsigned short)(old >> CNT_SHIFT);
}

// ---------------------------------------------------------------------------
// two-level exclusive scan of counts -> rowptr[n+1]; decode dinv from pcnt
__global__ void k_scanA(const unsigned long long* __restrict__ pcnt,
                        int* __restrict__ bsum, int n) {
    __shared__ int part[256];
    int tid = threadIdx.x;
    int base = blockIdx.x * 1024 + tid * 4;
    int s = 0;
    #pragma unroll
    for (int t = 0; t < 4; ++t) { int i = base + t; if (i < n) s += (int)(pcnt[i] >> CNT_SHIFT); }
    part[tid] = s; __syncthreads();
    for (int off = 128; off > 0; off >>= 1) {
        if (tid < off) part[tid] += part[tid + off];
        __syncthreads();
    }
    if (tid == 0) bsum[blockIdx.x] = part[0];
}

__global__ void k_scanB(int* bsum, int nb) {        // nb <= 256
    __shared__ int sh[256];
    int tid = threadIdx.x;
    int v = (tid < nb) ? bsum[tid] : 0;
    sh[tid] = v; __syncthreads();
    for (int off = 1; off < 256; off <<= 1) {
        int t = (tid >= off) ? sh[tid - off] : 0;
        __syncthreads();
        sh[tid] += t;
        __syncthreads();
    }
    if (tid < nb) bsum[tid] = sh[tid] - v;          // exclusive
}

__global__ void k_scanC(const unsigned long long* __restrict__ pcnt,
                        const int* __restrict__ bsum,
                        int* __restrict__ rowptr, float* __restrict__ dinv,
                        int n, int E_) {
    __shared__ int part[256];
    int tid = threadIdx.x;
    int base = blockIdx.x * 1024;
    int loc[4]; int s = 0;
    #pragma unroll
    for (int t = 0; t < 4; ++t) {
        int i = base + tid * 4 + t;
        int c = (i < n) ? (int)(pcnt[i] >> CNT_SHIFT) : 0;
        loc[t] = s; s += c;
    }
    part[tid] = s; __syncthreads();
    int mysum = s;
    for (int off = 1; off < 256; off <<= 1) {
        int t = (tid >= off) ? part[tid - off] : 0;
        __syncthreads();
        part[tid] += t;
        __syncthreads();
    }
    int thbase = bsum[blockIdx.x] + part[tid] - mysum;
    #pragma unroll
    for (int t = 0; t < 4; ++t) {
        int i = base + tid * 4 + t;
        if (i < n) {
            rowptr[i] = thbase + loc[t];
            // deg = 1 (self-loop) + fixed-point edge-weight sum; always >= 1
            float dg = 1.0f + (float)((double)(pcnt[i] & W_MASK) * W_INV);
            dinv[i] = rsqrtf(dg);
        }
    }
    if (blockIdx.x == 0 && tid == 0) rowptr[n] = E_;
}

// ---------------------------------------------------------------------------
// atomic-free scatter: pos = rowptr[d] + rank[e]
__global__ void k_scatter(const long long* ei64, const int* ei32, const int* flag,
                          const float* __restrict__ ew, const float* __restrict__ dinv,
                          const int* __restrict__ rowptr, const unsigned short* __restrict__ rank,
                          int2* __restrict__ csr, int E_) {
    int e = blockIdx.x * 256 + threadIdx.x;
    if (e >= E_) return;
    int f = *flag;
    int s = load_idx(ei64, ei32, f, e);
    int d = load_idx(ei64, ei32, f, (size_t)E_ + e);
    float w = dinv[s] * ew[e] * dinv[d];
    int pos = rowptr[d] + (int)rank[e];
    csr[pos] = make_int2(s, __float_as_int(w));
}

// ---------------------------------------------------------------------------
// AXb[i,:] = bf16( dinv[i]^2 * Xb[i,:] + sum_e w_e * Xb[src_e,:] )
__launch_bounds__(256)
__global__ void k_spmm(const int2* __restrict__ csr, const int* __restrict__ rowptr,
                       const float* __restrict__ dinv, const unsigned short* __restrict__ Xb,
                       unsigned short* __restrict__ AXb, int n) {
    int node = blockIdx.x * 4 + (threadIdx.x >> 6);
    int lane = threadIdx.x & 63;
    if (node >= n) return;
    float di = dinv[node];
    float acc = di * di * bf2f(Xb[(size_t)node * 64 + lane]);
    int j = rowptr[node], end = rowptr[node + 1];
    for (; j + 1 < end; j += 2) {
        int2 e0 = csr[j];
        int2 e1 = csr[j + 1];
        float x0 = bf2f(Xb[(size_t)e0.x * 64 + lane]);
        float x1 = bf2f(Xb[(size_t)e1.x * 64 + lane]);
        acc = fmaf(__int_as_float(e0.y), x0, acc);
        acc = fmaf(__int_as_float(e1.y), x1, acc);
    }
    if (j < end) {
        int2 e = csr[j];
        acc = fmaf(__int_as_float(e.y), bf2f(Xb[(size_t)e.x * 64 + lane]), acc);
    }
    AXb[(size_t)node * 64 + lane] = f2bf(acc);
}

// ---------------------------------------------------------------------------
// Weight prep, one block per gate (0..2) + head pack (block 3).
// gate: Wc = Wg @ Wl_top (LDS), bc = blg + bg @ Wl_top; pack 48 frags bf16.
// frag fi = nt*6+ks; (lane,j): k = ks*32+(lane>>4)*8+j, col = nt*16+(lane&15)
__launch_bounds__(512)
__global__ void k_wprep(const float* __restrict__ Wz, const float* __restrict__ Wr,
                        const float* __restrict__ Wh,
                        const float* __restrict__ Wlz, const float* __restrict__ Wlr,
                        const float* __restrict__ Wlh,
                        const float* __restrict__ bz, const float* __restrict__ br,
                        const float* __restrict__ bh,
                        const float* __restrict__ blz, const float* __restrict__ blr,
                        const float* __restrict__ blh,
                        const float* __restrict__ Whead,
                        short* __restrict__ Wpk, short* __restrict__ Hpk,
                        float* __restrict__ bc) {
    int tid = threadIdx.x;
    int gate = blockIdx.x;
    if (gate == 3) {   // head pack: K=128, 64 cols, 16 frags
        #pragma unroll
        for (int it = 0; it < 2; ++it) {
            int idx = it * 512 + tid;              // < 1024
            int fi = idx >> 6, lane = idx & 63;
            int nt = fi >> 2, ks = fi & 3;
            int col = nt * 16 + (lane & 15);
            int kb = ks * 32 + ((lane >> 4) * 8);
            short8v o;
            #pragma unroll
            for (int j = 0; j < 8; ++j) o[j] = (short)f2bf(Whead[(kb + j) * 64 + col]);
            *(short8v*)(Hpk + (size_t)fi * 512 + lane * 8) = o;
        }
        return;
    }
    const float* Wg  = gate == 0 ? Wz  : gate == 1 ? Wr  : Wh;
    const float* Wl  = gate == 0 ? Wlz : gate == 1 ? Wlr : Wlh;
    const float* bg  = gate == 0 ? bz  : gate == 1 ? br  : bh;
    const float* blg = gate == 0 ? blz : gate == 1 ? blr : blh;
    __shared__ float wc[64 * 128];
    for (int o = tid; o < 64 * 128; o += 512) {
        int r = o >> 7, j = o & 127;
        float s = 0.f;
        for (int k = 0; k < 128; ++k) s = fmaf(Wg[r * 128 + k], Wl[k * 128 + j], s);
        wc[o] = s;
    }
    if (tid < 128) {
        float s = blg[tid];
        for (int k = 0; k < 128; ++k) s = fmaf(bg[k], Wl[k * 128 + tid], s);
        bc[gate * 128 + tid] = s;
    }
    __syncthreads();
    short* out = Wpk + (size_t)gate * 48 * 512;
    #pragma unroll
    for (int it = 0; it < 6; ++it) {
        int idx = it * 512 + tid;                  // < 3072
        int fi = idx >> 6, lane = idx & 63;
        int nt = fi / 6, ks = fi - nt * 6;
        int col = nt * 16 + (lane & 15);
        int kb = ks * 32 + ((lane >> 4) * 8);
        short8v o;
        #pragma unroll
        for (int j = 0; j < 8; ++j) {
            int k = kb + j;
            float v = (k < 64) ? wc[k * 128 + col] : Wl[(64 + k) * 128 + col];
            o[j] = (short)f2bf(v);
        }
        *(short8v*)(out + (size_t)fi * 512 + lane * 8) = o;
    }
}

// ---------------------------------------------------------------------------
// Fused TGCN cell. 512 threads = 8 waves / 64-row block. Wave w: rows g=w>>1,
// N-half = w&1. A-fragments loaded per-lane directly from global (AXb bf16,
// H fp32->bf16); only HR/relu round-trips through LDS.
__launch_bounds__(512)
__global__ void k_cell(const unsigned short* __restrict__ AXb,   // N x 64 bf16
                       const float* __restrict__ Hm,             // N x 128
                       const short* __restrict__ Wpk,            // 3 x 48 x 512
                       const short* __restrict__ Hpk,            // 16 x 512
                       const float* __restrict__ bc,             // 3 x 128
                       const float* __restrict__ bhead,          // 64
                       float* __restrict__ Hn,                   // N x 128 out
                       float* __restrict__ Yout,                 // N x 64 out
                       int n) {
    __shared__ short HRs[64 * 136];   // [row][k2 0..127], 272B stride
    int tid = threadIdx.x;
    int w = tid >> 6, lane = tid & 63;
    int g = w >> 1, half = w & 1;
    int row0 = blockIdx.x * 64;

    int arow = g * 16 + (lane & 15);           // local row of this lane's A-frags
    int cr = row0 + arow; if (cr > n - 1) cr = n - 1;
    int kg = (lane >> 4) * 8;

    // ---- A-fragments: AX (2 frags, bf16 direct) + H (4 frags, converted) ----
    short8v afr0 = *(const short8v*)&AXb[(size_t)cr * 64 + kg];
    short8v afr1 = *(const short8v*)&AXb[(size_t)cr * 64 + 32 + kg];
    short8v ah[4];
    #pragma unroll
    for (int ks = 0; ks < 4; ++ks) {
        const float* hp = &Hm[(size_t)cr * 128 + ks * 32 + kg];
        float4 a = *(const float4*)hp;
        float4 b = *(const float4*)(hp + 4);
        short8v o;
        o[0] = (short)f2bf(a.x); o[1] = (short)f2bf(a.y);
        o[2] = (short)f2bf(a.z); o[3] = (short)f2bf(a.w);
        o[4] = (short)f2bf(b.x); o[5] = (short)f2bf(b.y);
        o[6] = (short)f2bf(b.z); o[7] = (short)f2bf(b.w);
        ah[ks] = o;
    }

    const short8v* Bz = (const short8v*)Wpk;
    const short8v* Br = (const short8v*)(Wpk + 48 * 512);
    const short8v* Bh = (const short8v*)(Wpk + 2 * 48 * 512);

    // ---- z & r gates: 4 nt-tiles per wave ----
    f32x4 accz[4] = {};
    f32x4 accr[4] = {};
    #pragma unroll
    for (int j = 0; j < 4; ++j) {
        int nt = half * 4 + j;
        accz[j] = MFMA_BF16(afr0,  Bz[(nt * 6 + 0) * 64 + lane], accz[j], 0, 0, 0);
        accz[j] = MFMA_BF16(afr1,  Bz[(nt * 6 + 1) * 64 + lane], accz[j], 0, 0, 0);
        #pragma unroll
        for (int ks = 0; ks < 4; ++ks)
            accz[j] = MFMA_BF16(ah[ks], Bz[(nt * 6 + 2 + ks) * 64 + lane], accz[j], 0, 0, 0);
        accr[j] = MFMA_BF16(afr0,  Br[(nt * 6 + 0) * 64 + lane], accr[j], 0, 0, 0);
        accr[j] = MFMA_BF16(afr1,  Br[(nt * 6 + 1) * 64 + lane], accr[j], 0, 0, 0);
        #pragma unroll
        for (int ks = 0; ks < 4; ++ks)
            accr[j] = MFMA_BF16(ah[ks], Br[(nt * 6 + 2 + ks) * 64 + lane], accr[j], 0, 0, 0);
    }

    // ---- z/r epilogue: Z stays in accz regs, HR -> LDS bf16 ----
    #pragma unroll
    for (int j = 0; j < 4; ++j) {
        int col = (half * 4 + j) * 16 + (lane & 15);
        float bzv = bc[col];
        float brv = bc[128 + col];
        #pragma unroll
        for (int i = 0; i < 4; ++i) {
            int lrow = g * 16 + (lane >> 4) * 4 + i;
            int grow = row0 + lrow;
            float z = fsigmoid(accz[j][i] + bzv);
            float hv = (grow < n) ? Hm[(size_t)grow * 128 + col] : 0.f;
            float hr = hv * fsigmoid(accr[j][i] + brv);
            accz[j][i] = z;
            HRs[lrow * 136 + col] = (short)f2bf(hr);
        }
    }
    __syncthreads();                       // HR complete (both halves)

    // ---- h gate: A = [AX | HR] ----
    short8v ahr[4];
    #pragma unroll
    for (int ks = 0; ks < 4; ++ks)
        ahr[ks] = *(const short8v*)&HRs[arow * 136 + ks * 32 + kg];
    f32x4 acch[4] = {};
    #pragma unroll
    for (int j = 0; j < 4; ++j) {
        int nt = half * 4 + j;
        acch[j] = MFMA_BF16(afr0,   Bh[(nt * 6 + 0) * 64 + lane], acch[j], 0, 0, 0);
        acch[j] = MFMA_BF16(afr1,   Bh[(nt * 6 + 1) * 64 + lane], acch[j], 0, 0, 0);
        #pragma unroll
        for (int ks = 0; ks < 4; ++ks)
            acch[j] = MFMA_BF16(ahr[ks], Bh[(nt * 6 + 2 + ks) * 64 + lane], acch[j], 0, 0, 0);
    }
    __syncthreads();                       // all HR reads done before overwrite

    // ---- h epilogue: Hn -> global, relu(Hn) -> LDS (reuse HRs) ----
    #pragma unroll
    for (int j = 0; j < 4; ++j) {
        int col = (half * 4 + j) * 16 + (lane & 15);
        float bhv = bc[256 + col];
        #pragma unroll
        for (int i = 0; i < 4; ++i) {
            int lrow = g * 16 + (lane >> 4) * 4 + i;
            int grow = row0 + lrow;
            float th = ftanh(acch[j][i] + bhv);
            float z = accz[j][i];
            float hv = (grow < n) ? Hm[(size_t)grow * 128 + col] : 0.f;
            float hn = z * hv + (1.f - z) * th;
            if (grow < n) Hn[(size_t)grow * 128 + col] = hn;
            HRs[lrow * 136 + col] = (short)f2bf(fmaxf(hn, 0.f));
        }
    }
    __syncthreads();                       // relu(Hn) complete

    // ---- head: Y = relu(Hn) @ Bhead + bhead (2 nt-tiles per wave) ----
    short8v ay[4];
    #pragma unroll
    for (int ks = 0; ks < 4; ++ks)
        ay[ks] = *(const short8v*)&HRs[arow * 136 + ks * 32 + kg];
    const short8v* By = (const short8v*)Hpk;
    f32x4 accy[2] = {};
    #pragma unroll
    for (int j = 0; j < 2; ++j) {
        int nt = half * 2 + j;
        #pragma unroll
        for (int ks = 0; ks < 4; ++ks)
            accy[j] = MFMA_BF16(ay[ks], By[(nt * 4 + ks) * 64 + lane], accy[j], 0, 0, 0);
    }
    #pragma unroll
    for (int j = 0; j < 2; ++j) {
        int col = (half * 2 + j) * 16 + (lane & 15);
        float by = bhead[col];
        #pragma unroll
        for (int i = 0; i < 4; ++i) {
            int grow = row0 + g * 16 + (lane >> 4) * 4 + i;
            if (grow < n) Yout[(size_t)grow * 64 + col] = accy[j][i] + by;
        }
    }
}

// ---------------------------------------------------------------------------
extern "C" void kernel_launch(void* const* d_in, const int* in_sizes, int n_in,
                              void* d_out, int out_size, void* d_ws, size_t ws_size,
                              hipStream_t stream) {
    const float* node_feat   = (const float*)d_in[0];
    const float* edge_weight = (const float*)d_in[1];
    const float* H           = (const float*)d_in[2];
    const void*  ei          = d_in[3];
    const float* Wz   = (const float*)d_in[4];  const float* bz = (const float*)d_in[5];
    const float* Wr   = (const float*)d_in[6];  const float* br = (const float*)d_in[7];
    const float* Wh   = (const float*)d_in[8];  const float* bh = (const float*)d_in[9];
    const float* Wlz  = (const float*)d_in[10]; const float* blz = (const float*)d_in[11];
    const float* Wlr  = (const float*)d_in[12]; const float* blr = (const float*)d_in[13];
    const float* Wlh  = (const float*)d_in[14]; const float* blh = (const float*)d_in[15];
    const float* Whead = (const float*)d_in[16]; const float* bhead = (const float*)d_in[17];

    const int N = in_sizes[0] / F;    // 100000
    const int E = in_sizes[1];        // 1600000
    const int NB = (N + 1023) / 1024;

    float* ws   = (float*)d_ws;
    int*   flag = (int*)ws;                                 // [64 floats pad]
    unsigned long long* pcnt = (unsigned long long*)(ws + 64);  // N u64 (8B aligned)
    float* dinv = ws + 64 + 2 * (size_t)N;                  // N
    int*   rowptr = (int*)(dinv + N);                       // N+1
    int*   bsum   = rowptr + N + 1;                         // 256
    float* bc   = (float*)(bsum + 256);                     // 3 x 128
    size_t pk_off = (size_t)((bc + 3 * 128) - ws);
    pk_off = (pk_off + 3) & ~(size_t)3;                     // 16B align
    short* Wpk  = (short*)(ws + pk_off);                    // 3 x 48*512 bf16
    short* Hpk  = Wpk + 3 * 48 * 512;                       // 16*512 bf16
    size_t rk_off = pk_off + (3 * 48 * 512 + 16 * 512) / 2;
    unsigned short* rank = (unsigned short*)(ws + rk_off);  // E u16
    size_t xb_off = rk_off + ((size_t)E + 1) / 2;
    unsigned short* Xb  = (unsigned short*)(ws + xb_off);   // N*64 bf16
    unsigned short* AXb = Xb + (size_t)N * 64;              // N*64 bf16
    size_t csr_off = xb_off + (size_t)N * 64;               // (2 x N*64 u16 = N*64 floats)
    csr_off = (csr_off + 1) & ~(size_t)1;                   // 8B align
    int2*  csr  = (int2*)(ws + csr_off);                    // E int2

    float* Y  = (float*)d_out;                              // N*64
    float* Hn = Y + (size_t)N * F;                          // N*128

    const long long* ei64 = (const long long*)ei;
    const int*       ei32 = (const int*)ei;

    k_detect<<<1, 256, 0, stream>>>((const unsigned long long*)ei, 1024,
                                    (unsigned long long)N, flag);
    k_prep<<<(N * 16 + 255) / 256, 256, 0, stream>>>(node_feat, Xb, pcnt, N);
    k_hist<<<(E + 255) / 256, 256, 0, stream>>>(ei64, ei32, flag, edge_weight,
                                                pcnt, rank, E);
    k_scanA<<<NB, 256, 0, stream>>>(pcnt, bsum, N);
    k_scanB<<<1, 256, 0, stream>>>(bsum, NB);
    k_scanC<<<NB, 256, 0, stream>>>(pcnt, bsum, rowptr, dinv, N, E);
    k_scatter<<<(E + 255) / 256, 256, 0, stream>>>(ei64, ei32, flag, edge_weight, dinv,
                                                   rowptr, rank, csr, E);
    k_spmm<<<(N + 3) / 4, 256, 0, stream>>>(csr, rowptr, dinv, Xb, AXb, N);

    k_wprep<<<4, 512, 0, stream>>>(Wz, Wr, Wh, Wlz, Wlr, Wlh,
                                   bz, br, bh, blz, blr, blh, Whead, Wpk, Hpk, bc);

    k_cell<<<(N + 63) / 64, 512, 0, stream>>>(AXb, H, Wpk, Hpk, bc, bhead, Hn, Y, N);
}